// Round 6
// baseline (400.457 us; speedup 1.0000x reference)
//
#include <hip/hip_runtime.h>
#include <hip/hip_bf16.h>

#define N_NODES 50000
#define N_EDGES 640000
#define HID 128
#define EDG 128          // edges per edge-block

typedef unsigned short ushort_t;
typedef __attribute__((ext_vector_type(8))) short bf16x8;   // 8 bf16 = 4 VGPR (MFMA A/B frag)
typedef __attribute__((ext_vector_type(4))) float f32x4;    // MFMA C/D frag

// ws layout (ushort units from base):
//   maggr  [0,        6400000)   bf16 N x 128 (pk-atomic accumulated)
//   hb     [6400000, 12800000)   bf16 N x 128 (h pre-converted)
//   w1b    [12800000,12832768)   Wab 256 x 128: rows 0..127 = ew1[:,0:128] (A), rows 128..255 = ew1[:,128:256] (B)
//   w2b    [12832768,12849152)   128 x 128
//   w3b    [12849152,12865536)   128 x 128
//   c1b    [12865536,12881920)   128 x 128 (bf16 cw1; consumed by wc block)
//   n1b    [12881920,12914688)   128 x 256
//   n2b    [12914688,12931072)   128 x 128
//   n3b    [12931072,12947456)   128 x 128
//   w1d2   (float*) at ushort 12947456, 128 f32 = ew1[:,256]
//   wcb    [12947712,12964096)   128 x 128 bf16 = Wc1 @ W3 (composed coord weight)
//   bc     (float*) at ushort 12964096, 128 f32 = Wc1 @ eb3 + cb1
//   sd     [12964352,15524352)   int2[640000] src-sorted (src,dst) pairs
//   cnt    [15524352,15624448)   u32[50048]  per-src degree histogram
//   ptr    [15624448,15724544)   u32[50048]  scatter cursors (exclusive scan)
// AB table (bf16 N x 256 = 25.6 MB) lives in d_out's hout region (dead until node_kernel
// fully overwrites it): A[n] = h@W1a^T in feats 0..127, B[n] = h@W1b^T + eb1 in feats 128..255.
#define U_MAGGR 0
#define U_HB    6400000
#define U_W1B   12800000
#define U_W2B   12832768
#define U_W3B   12849152
#define U_C1B   12865536
#define U_N1B   12881920
#define U_N2B   12914688
#define U_N3B   12931072
#define U_W1D2  12947456
#define U_WC    12947712
#define U_BC    12964096
#define U_SD    12964352
#define U_CNT   15524352
#define U_PTR   15624448

// silu via exp2 + fast rcp (bf16-output tolerance; saves div fixup sequence)
__device__ __forceinline__ float silu_f(float v) {
    const float e = __builtin_amdgcn_exp2f(v * -1.442695041f);
    return v * __builtin_amdgcn_rcpf(1.0f + e);
}

__device__ __forceinline__ ushort_t f2b(float f) {
    __hip_bfloat16 b = __float2bfloat16(f);          // RNE
    return __builtin_bit_cast(ushort_t, b);
}
__device__ __forceinline__ float b2f(ushort_t u) {
    union { float f; unsigned int i; } v; v.i = ((unsigned int)u) << 16; return v.f;
}
__device__ __forceinline__ float u2f(unsigned int u) {
    union { float f; unsigned int i; } v; v.i = u; return v.f;
}
__device__ __forceinline__ unsigned int pack2(float a, float b) {
    return (unsigned int)f2b(a) | ((unsigned int)f2b(b) << 16);
}
// uint4 of 8 bf16 -> 8 f32 (1 VALU op each: shl or and)
__device__ __forceinline__ void up8(const uint4& u, float* f) {
    f[0] = u2f(u.x << 16); f[1] = u2f(u.x & 0xffff0000u);
    f[2] = u2f(u.y << 16); f[3] = u2f(u.y & 0xffff0000u);
    f[4] = u2f(u.z << 16); f[5] = u2f(u.z & 0xffff0000u);
    f[6] = u2f(u.w << 16); f[7] = u2f(u.w & 0xffff0000u);
}
__device__ __forceinline__ void atom_add_f32(float* p, float v) { unsafeAtomicAdd(p, v); }

// packed bf16x2 atomic add (gfx950: global_atomic_pk_add_bf16)
__device__ __forceinline__ void atom_pk_bf16(ushort_t* p, unsigned int v) {
#if __has_builtin(__builtin_amdgcn_global_atomic_fadd_v2bf16)
    typedef __attribute__((ext_vector_type(2))) short s2;
    s2 sv = __builtin_bit_cast(s2, v);
    __builtin_amdgcn_global_atomic_fadd_v2bf16((__attribute__((address_space(1))) s2*)p, sv);
#else
    unsigned int* up = (unsigned int*)p;
    unsigned int old = __hip_atomic_load(up, __ATOMIC_RELAXED, __HIP_MEMORY_SCOPE_AGENT), assumed;
    do {
        assumed = old;
        float lo = b2f((ushort_t)(assumed & 0xffff)) + b2f((ushort_t)(v & 0xffff));
        float hi = b2f((ushort_t)(assumed >> 16)) + b2f((ushort_t)(v >> 16));
        unsigned int nv = (unsigned int)f2b(lo) | ((unsigned int)f2b(hi) << 16);
        old = atomicCAS(up, assumed, nv);
    } while (old != assumed);
#endif
}

// ---------------- prep (vectorized; incl. src histogram; cnt pre-zeroed via memset) ----------------
__global__ void prep_kernel(const float* __restrict__ x, const float* __restrict__ h,
                            const float* __restrict__ ew1, const float* __restrict__ ew2,
                            const float* __restrict__ ew3, const float* __restrict__ cw1,
                            const float* __restrict__ nw1, const float* __restrict__ nw2,
                            const float* __restrict__ nw3, const int* __restrict__ ei,
                            ushort_t* __restrict__ wsu, float* __restrict__ xout) {
    long i = (long)blockIdx.x * 256 + threadIdx.x;
    if (i < 800000) {   // maggr zero, 16B stores
        ((uint4*)(wsu + U_MAGGR))[i] = make_uint4(0u, 0u, 0u, 0u);
        return;
    }
    i -= 800000;
    if (i < 800000) {   // h -> bf16, 8 floats per thread
        const float4* h4 = (const float4*)h;
        const float4 f0 = h4[2 * i], f1 = h4[2 * i + 1];
        ((uint4*)(wsu + U_HB))[i] = make_uint4(pack2(f0.x, f0.y), pack2(f0.z, f0.w),
                                               pack2(f1.x, f1.y), pack2(f1.z, f1.w));
        return;
    }
    i -= 800000;
    if (i < 32768) {
        // Wab[f][k]: f<128 -> ew1[f][k] (A half), f>=128 -> ew1[f-128][128+k] (B half)
        const int f = (int)(i >> 7);
        const int k = (int)(i & 127);
        const int src = (f < 128) ? (f * 257 + k) : ((f - 128) * 257 + 128 + k);
        wsu[U_W1B + i] = f2b(ew1[src]);
        return;
    }
    i -= 32768;
    if (i < 16384) { wsu[U_W2B + i] = f2b(ew2[i]); return; }
    i -= 16384;
    if (i < 16384) { wsu[U_W3B + i] = f2b(ew3[i]); return; }
    i -= 16384;
    if (i < 16384) { wsu[U_C1B + i] = f2b(cw1[i]); return; }
    i -= 16384;
    if (i < 32768) { wsu[U_N1B + i] = f2b(nw1[i]); return; }
    i -= 32768;
    if (i < 16384) { wsu[U_N2B + i] = f2b(nw2[i]); return; }
    i -= 16384;
    if (i < 16384) { wsu[U_N3B + i] = f2b(nw3[i]); return; }
    i -= 16384;
    if (i < 128) { ((float*)(wsu + U_W1D2))[i] = ew1[i * 257 + 256]; return; }
    i -= 128;
    if (i < 37500) { ((float4*)xout)[i] = ((const float4*)x)[i]; return; }
    i -= 37500;
    if (i < N_EDGES) {
        atomicAdd(((unsigned int*)(wsu + U_CNT)) + ei[i], 1u);
    }
}

// ---------------- exclusive scan cnt -> ptr (1 block x 1024 threads, ~49 elems/thread) ----------------
__global__ __launch_bounds__(1024) void scan_kernel(const unsigned int* __restrict__ cnt,
                                                    unsigned int* __restrict__ ptr) {
    __shared__ unsigned int sSum[1024];
    const int t = threadIdx.x;
    const int lo = t * 49;
    const int hi = (lo + 49 < N_NODES) ? lo + 49 : N_NODES;
    unsigned int s = 0;
    for (int i = lo; i < hi; ++i) s += cnt[i];
    sSum[t] = s;
    __syncthreads();
#pragma unroll
    for (int off = 1; off < 1024; off <<= 1) {
        const unsigned int v = (t >= off) ? sSum[t - off] : 0u;
        __syncthreads();
        sSum[t] += v;
        __syncthreads();
    }
    unsigned int run = (t == 0) ? 0u : sSum[t - 1];
    for (int i = lo; i < hi; ++i) { const unsigned int c = cnt[i]; ptr[i] = run; run += c; }
}

// ---------------- merged AB precompute + Wc compose + scatter ----------------
// Blocks 0..nAB-1:   AB[n] = [h@W1a^T | h@W1b^T + eb1]   (64 nodes/block, 4 waves)
// Block nAB:         Wc = Wc1 @ W3 (bf16) and bc = Wc1 @ eb3 + cb1
// Blocks nAB+1..:    counting-sort scatter (overlaps with AB MFMA work)
__global__ __launch_bounds__(256, 4) void abscatter_kernel(
    const ushort_t* __restrict__ hb, const ushort_t* __restrict__ wab,
    const float* __restrict__ eb1, ushort_t* __restrict__ abp,
    const ushort_t* __restrict__ c1b, const float* __restrict__ ew3,
    const float* __restrict__ eb3, const float* __restrict__ cb1,
    ushort_t* __restrict__ wcb, float* __restrict__ bcv,
    const int* __restrict__ ei, unsigned int* __restrict__ ptr, int2* __restrict__ sd,
    int nAB) {
    __shared__ ushort_t sH[16384];   // AB path uses first 8192; Wc block uses all 32 KB
    const int t = threadIdx.x;

    if ((int)blockIdx.x > nAB) {
        // ---- scatter role ----
        const int e = ((int)blockIdx.x - nAB - 1) * 256 + t;
        if (e < N_EDGES) {
            const int s = ei[e], d = ei[N_EDGES + e];
            const unsigned int pos = atomicAdd(&ptr[s], 1u);
            sd[pos] = make_int2(s, d);
        }
        return;
    }

    const int lane = t & 63;
    const int wid = t >> 6;          // 0..3
    const int r15 = lane & 15;
    const int khi = lane >> 4;
    const int rhi = khi * 4;

    if ((int)blockIdx.x == nAB) {
        // ---- stage Bt[k][m] = ew3[m][k] bf16, XOR-swizzled ----
        for (int i = t; i < 16384; i += 256) {
            const int m = i >> 7, k = i & 127;
            sH[(k * 128 + m) ^ ((k & 7) << 3)] = f2b(ew3[i]);
        }
        __syncthreads();
        // ---- Wc[f][k] = sum_m Wc1[f][m] * W3[m][k] ----
#pragma unroll
        for (int kh = 0; kh < 2; ++kh) {
#pragma unroll
            for (int fi = 0; fi < 2; ++fi) {
                const int f0 = wid * 32 + fi * 16;
                const int kc = kh * 64;
                f32x4 acc[4];
#pragma unroll
                for (int ni = 0; ni < 4; ++ni) acc[ni] = (f32x4){0.f, 0.f, 0.f, 0.f};
#pragma unroll
                for (int ks = 0; ks < 4; ++ks) {
                    const bf16x8 a0 = *(const bf16x8*)(c1b + (f0 + r15) * 128 + ks * 32 + khi * 8);
                    bf16x8 b[4];
#pragma unroll
                    for (int ni = 0; ni < 4; ++ni) {
                        const int kk = kc + ni * 16 + r15;
                        b[ni] = *(const bf16x8*)(sH + ((kk * 128 + ks * 32 + khi * 8) ^ ((kk & 7) << 3)));
                    }
#pragma unroll
                    for (int ni = 0; ni < 4; ++ni)
                        acc[ni] = __builtin_amdgcn_mfma_f32_16x16x32_bf16(a0, b[ni], acc[ni], 0, 0, 0);
                }
#pragma unroll
                for (int ni = 0; ni < 4; ++ni) {
                    const int kk = kc + ni * 16 + r15;
#pragma unroll
                    for (int j = 0; j < 4; ++j)
                        wcb[(f0 + rhi + j) * 128 + kk] = f2b(acc[ni][j]);
                }
            }
        }
        // ---- bc[f] = cb1[f] + sum_m Wc1[f][m] * eb3[m] ----
        {
            const int f = t >> 1, hf = t & 1;
            float s = 0.f;
            const int m0 = hf * 64;
#pragma unroll 8
            for (int m = m0; m < m0 + 64; ++m)
                s = fmaf(b2f(c1b[f * 128 + m]), eb3[m], s);
            s += __shfl_xor(s, 1);
            if (hf == 0) bcv[f] = cb1[f] + s;
        }
        return;
    }

    const int fb = wid * 64;         // 64 feats per wave (4 row-blocks)
    const int n0 = blockIdx.x * 64;

    const uint4* hb4 = (const uint4*)hb;
#pragma unroll
    for (int it = 0; it < 4; ++it) {
        const int idx = it * 256 + t;          // 1024 tasks: 64 nodes x 16 chunks
        const int e = idx >> 4, c = idx & 15;
        const int n = n0 + e;
        uint4 v = make_uint4(0u, 0u, 0u, 0u);
        if (n < N_NODES) v = hb4[(size_t)n * 16 + c];
        const int ui = (e * 128 + c * 8) ^ ((e & 7) << 3);
        *(uint4*)(sH + ui) = v;
    }
    __syncthreads();

    f32x4 acc[4][4];
#pragma unroll
    for (int mi = 0; mi < 4; ++mi)
#pragma unroll
        for (int ni = 0; ni < 4; ++ni) acc[mi][ni] = (f32x4){0.f, 0.f, 0.f, 0.f};
#pragma unroll
    for (int ks = 0; ks < 4; ++ks) {
        bf16x8 a[4];
#pragma unroll
        for (int mi = 0; mi < 4; ++mi)
            a[mi] = *(const bf16x8*)(wab + (fb + mi * 16 + r15) * 128 + ks * 32 + khi * 8);
        bf16x8 b[4];
#pragma unroll
        for (int ni = 0; ni < 4; ++ni) {
            const int e = ni * 16 + r15;
            const int ui = (e * 128 + ks * 32 + khi * 8) ^ ((e & 7) << 3);
            b[ni] = *(const bf16x8*)(sH + ui);
        }
#pragma unroll
        for (int mi = 0; mi < 4; ++mi)
#pragma unroll
            for (int ni = 0; ni < 4; ++ni)
                acc[mi][ni] = __builtin_amdgcn_mfma_f32_16x16x32_bf16(a[mi], b[ni], acc[mi][ni], 0, 0, 0);
    }

#pragma unroll
    for (int mi = 0; mi < 4; ++mi) {
        const int f0 = fb + mi * 16 + rhi;     // entire 16-block is on one side of 128
        float4 bb = make_float4(0.f, 0.f, 0.f, 0.f);
        if (f0 >= 128) bb = *(const float4*)&eb1[f0 - 128];
#pragma unroll
        for (int ni = 0; ni < 4; ++ni) {
            const int n = n0 + ni * 16 + r15;
            if (n < N_NODES) {
                *(uint2*)(abp + (size_t)n * 256 + f0) =
                    make_uint2(pack2(acc[mi][ni][0] + bb.x, acc[mi][ni][1] + bb.y),
                               pack2(acc[mi][ni][2] + bb.z, acc[mi][ni][3] + bb.w));
            }
        }
    }
}

// swapped dense layer, K=128, wave tile = 32 feats x 64 edges:
// (2 A + 4 B) reads per k-step instead of (1 A + 8 B) -> 33% fewer LDS reads.
// src rows: [128 edges][128 ushorts], XOR-swizzled ^((edge&7)<<3) (ushort units).
template <bool ACT>
__device__ __forceinline__ void dense32x64(ushort_t* sE, int srcBase, int dstBase,
                                           const ushort_t* __restrict__ W,
                                           const float* __restrict__ bias,
                                           int r15, int khi, int rhi, int fb, int eb) {
    f32x4 acc[2][4];
#pragma unroll
    for (int mi = 0; mi < 2; ++mi)
#pragma unroll
        for (int ni = 0; ni < 4; ++ni) acc[mi][ni] = (f32x4){0.f, 0.f, 0.f, 0.f};
#pragma unroll
    for (int ks = 0; ks < 4; ++ks) {
        const bf16x8 a0 = *(const bf16x8*)(W + (fb + r15) * 128 + ks * 32 + khi * 8);
        const bf16x8 a1 = *(const bf16x8*)(W + (fb + 16 + r15) * 128 + ks * 32 + khi * 8);
        bf16x8 b[4];
#pragma unroll
        for (int ni = 0; ni < 4; ++ni) {
            const int edge = eb + ni * 16 + r15;
            const int ui = (srcBase + edge * 128 + ks * 32 + khi * 8) ^ ((edge & 7) << 3);
            b[ni] = *(const bf16x8*)(sE + ui);
        }
#pragma unroll
        for (int ni = 0; ni < 4; ++ni) {
            acc[0][ni] = __builtin_amdgcn_mfma_f32_16x16x32_bf16(a0, b[ni], acc[0][ni], 0, 0, 0);
            acc[1][ni] = __builtin_amdgcn_mfma_f32_16x16x32_bf16(a1, b[ni], acc[1][ni], 0, 0, 0);
        }
    }
    const float4 bb0 = *(const float4*)&bias[fb + rhi];
    const float4 bb1 = *(const float4*)&bias[fb + 16 + rhi];
#pragma unroll
    for (int mi = 0; mi < 2; ++mi) {
        const float4 bb = mi ? bb1 : bb0;
#pragma unroll
        for (int ni = 0; ni < 4; ++ni) {
            const int edge = eb + ni * 16 + r15;
            float v0 = acc[mi][ni][0] + bb.x;
            float v1 = acc[mi][ni][1] + bb.y;
            float v2 = acc[mi][ni][2] + bb.z;
            float v3 = acc[mi][ni][3] + bb.w;
            if (ACT) { v0 = silu_f(v0); v1 = silu_f(v1); v2 = silu_f(v2); v3 = silu_f(v3); }
            const int ui = (dstBase + edge * 128 + fb + mi * 16 + rhi) ^ ((edge & 7) << 3);
            *(uint2*)(sE + ui) = make_uint2(pack2(v0, v1), pack2(v2, v3));
        }
    }
}

// ---------------- edge ----------------
// 512 threads / 8 waves per block, 128 src-sorted edges per block (2 blocks/CU).
// Wave (fg = wid&3, eh = wid>>2) owns feats fg*32..+32 x edges eh*64..+64.
// Phases: P0 gather-issue+meta | P1 act1 stage | P2 w2 | P3 w3->LDS + c1'(composed)->dot
//         P4 segmented aggr (f32 partials -> ~1 atomic per segment) + segmented xout
__global__ __launch_bounds__(512, 4) void edge_kernel(
    const float* __restrict__ x, const ushort_t* __restrict__ ab,
    const int2* __restrict__ sd,
    const float* __restrict__ w1d2,
    const ushort_t* __restrict__ w2b, const float* __restrict__ eb2,
    const ushort_t* __restrict__ w3b, const float* __restrict__ eb3,
    const ushort_t* __restrict__ wcb, const float* __restrict__ bcv,
    const float* __restrict__ cw2, const float* __restrict__ cb2,
    float* __restrict__ xout, ushort_t* __restrict__ maggr) {
    __shared__ ushort_t sE[32768];   // 64 KB: act1/m_ij @0, act2 @16384 ([128][128] each)
    __shared__ float srel[EDG][3];
    __shared__ float sd2[EDG];
    __shared__ int ssrc[EDG];
    __shared__ float sPart[4][EDG];  // per-feat-group partials; rows 0..2 reused for xout

    const int t = threadIdx.x;
    const int lane = t & 63;
    const int wid = t >> 6;          // 0..7
    const int r15 = lane & 15;
    const int khi = lane >> 4;       // 0..3
    const int rhi = khi * 4;
    const int fg = wid & 3;
    const int eh = wid >> 2;
    const int fb = fg * 32;          // 32 feats per wave
    const int eb = eh * 64;          // 64 edges per wave
    const int e0 = blockIdx.x * EDG;

    // ---- P0: issue AB gathers; c = t&15 is iteration-invariant, e = it*32 + (t>>4).
    //          t<EDG concurrently builds srel/sd2/ssrc.
    uint4 va[4], vb[4];
    const int c = t & 15;
    const int ebase = t >> 4;        // 0..31
    {
        const uint4* ab4 = (const uint4*)ab;
#pragma unroll
        for (int it = 0; it < 4; ++it) {
            const int e = it * 32 + ebase;
            const int2 p = sd[e0 + e];
            va[it] = ab4[(size_t)p.x * 32 + c];         // A half of AB[src]
            vb[it] = ab4[(size_t)p.y * 32 + 16 + c];    // B half of AB[dst]
        }
    }
    if (t < EDG) {
        const int2 p = sd[e0 + t];
        ssrc[t] = p.x;
        const float rx = x[3 * p.x] - x[3 * p.y];
        const float ry = x[3 * p.x + 1] - x[3 * p.y + 1];
        const float rz = x[3 * p.x + 2] - x[3 * p.y + 2];
        srel[t][0] = rx; srel[t][1] = ry; srel[t][2] = rz;
        sd2[t] = rx * rx + ry * ry + rz * rz;
    }
    __syncthreads();

    // ---- P1: act1 = silu(A[src] + B[dst] + d2*w1d2); w1d2 loads hoisted (c fixed) ----
    {
        const float4 w0 = *(const float4*)&w1d2[c * 8];
        const float4 w1 = *(const float4*)&w1d2[c * 8 + 4];
#pragma unroll
        for (int it = 0; it < 4; ++it) {
            const int e = it * 32 + ebase;
            const float d2 = sd2[e];
            float fa[8], fbv[8];
            up8(va[it], fa);
            up8(vb[it], fbv);
            const float v0 = silu_f(fmaf(d2, w0.x, fa[0] + fbv[0]));
            const float v1 = silu_f(fmaf(d2, w0.y, fa[1] + fbv[1]));
            const float v2 = silu_f(fmaf(d2, w0.z, fa[2] + fbv[2]));
            const float v3 = silu_f(fmaf(d2, w0.w, fa[3] + fbv[3]));
            const float v4 = silu_f(fmaf(d2, w1.x, fa[4] + fbv[4]));
            const float v5 = silu_f(fmaf(d2, w1.y, fa[5] + fbv[5]));
            const float v6 = silu_f(fmaf(d2, w1.z, fa[6] + fbv[6]));
            const float v7 = silu_f(fmaf(d2, w1.w, fa[7] + fbv[7]));
            uint4 st;
            st.x = pack2(v0, v1); st.y = pack2(v2, v3);
            st.z = pack2(v4, v5); st.w = pack2(v6, v7);
            *(uint4*)(sE + ((e * 128 + c * 8) ^ ((e & 7) << 3))) = st;
        }
    }
    __syncthreads();

    // ---- P2: w2 dense: act1 -> silu -> act2 @16384 ----
    dense32x64<true>(sE, 0, 16384, w2b, eb2, r15, khi, rhi, fb, eb);
    __syncthreads();

    // ---- P3a: w3 dense: act2 -> m_ij @0 (packed LDS store) ----
    dense32x64<false>(sE, 16384, 0, w3b, eb3, r15, khi, rhi, fb, eb);

    // ---- P3b: c1' dense with composed Wc (reads act2 directly) -> silu -> dot(cw2) ----
    {
        f32x4 acc[2][4];
#pragma unroll
        for (int mi = 0; mi < 2; ++mi)
#pragma unroll
            for (int ni = 0; ni < 4; ++ni) acc[mi][ni] = (f32x4){0.f, 0.f, 0.f, 0.f};
#pragma unroll
        for (int ks = 0; ks < 4; ++ks) {
            const bf16x8 a0 = *(const bf16x8*)(wcb + (fb + r15) * 128 + ks * 32 + khi * 8);
            const bf16x8 a1 = *(const bf16x8*)(wcb + (fb + 16 + r15) * 128 + ks * 32 + khi * 8);
            bf16x8 b[4];
#pragma unroll
            for (int ni = 0; ni < 4; ++ni) {
                const int edge = eb + ni * 16 + r15;
                const int u = (16384 + edge * 128 + ks * 32 + khi * 8) ^ ((edge & 7) << 3);
                b[ni] = *(const bf16x8*)(sE + u);
            }
#pragma unroll
            for (int ni = 0; ni < 4; ++ni) {
                acc[0][ni] = __builtin_amdgcn_mfma_f32_16x16x32_bf16(a0, b[ni], acc[0][ni], 0, 0, 0);
                acc[1][ni] = __builtin_amdgcn_mfma_f32_16x16x32_bf16(a1, b[ni], acc[1][ni], 0, 0, 0);
            }
        }
        const float4 bb0 = *(const float4*)&bcv[fb + rhi];
        const float4 bb1 = *(const float4*)&bcv[fb + 16 + rhi];
        const float4 cw0 = *(const float4*)&cw2[fb + rhi];
        const float4 cw1v = *(const float4*)&cw2[fb + 16 + rhi];
        float p[4];
#pragma unroll
        for (int ni = 0; ni < 4; ++ni) {
            float s = silu_f(acc[0][ni][0] + bb0.x) * cw0.x;
            s = fmaf(silu_f(acc[0][ni][1] + bb0.y), cw0.y, s);
            s = fmaf(silu_f(acc[0][ni][2] + bb0.z), cw0.z, s);
            s = fmaf(silu_f(acc[0][ni][3] + bb0.w), cw0.w, s);
            s = fmaf(silu_f(acc[1][ni][0] + bb1.x), cw1v.x, s);
            s = fmaf(silu_f(acc[1][ni][1] + bb1.y), cw1v.y, s);
            s = fmaf(silu_f(acc[1][ni][2] + bb1.z), cw1v.z, s);
            s = fmaf(silu_f(acc[1][ni][3] + bb1.w), cw1v.w, s);
            p[ni] = s;
        }
#pragma unroll
        for (int ni = 0; ni < 4; ++ni) {
            p[ni] += __shfl_xor(p[ni], 16);
            p[ni] += __shfl_xor(p[ni], 32);
        }
        if (khi == 0) {
#pragma unroll
            for (int ni = 0; ni < 4; ++ni) sPart[fg][eb + ni * 16 + r15] = p[ni];
        }
    }
    __syncthreads();

    // coef + per-edge xout contributions into sPart rows 0..2 (column-private)
    if (t < EDG) {
        const float s = sPart[0][t] + sPart[1][t] + sPart[2][t] + sPart[3][t];
        const float coef = tanhf(s + cb2[0]);
        sPart[0][t] = srel[t][0] * coef;
        sPart[1][t] = srel[t][1] * coef;
        sPart[2][t] = srel[t][2] * coef;
    }

    // ---- P4: segmented maggr aggregation. thread = (dw 0..63, strip 0..7), 16 edges/strip;
    //          f32 partials per src-segment, one pk-atomic per boundary. Wave-uniform branches.
    {
        const int dw = t & 63;
        const int rs = t >> 6;
        float lo = 0.f, hi = 0.f;
        int cur = ssrc[rs * 16];
#pragma unroll
        for (int j = 0; j < 16; ++j) {
            const int e = rs * 16 + j;
            const int s = ssrc[e];
            if (s != cur) {
                atom_pk_bf16(maggr + (size_t)cur * 128 + dw * 2, pack2(lo, hi));
                lo = 0.f; hi = 0.f; cur = s;
            }
            const unsigned int v = *(const unsigned int*)(sE + ((e * 128 + dw * 2) ^ ((e & 7) << 3)));
            lo += b2f((ushort_t)(v & 0xffff));
            hi += b2f((ushort_t)(v >> 16));
        }
        atom_pk_bf16(maggr + (size_t)cur * 128 + dw * 2, pack2(lo, hi));
    }
    __syncthreads();

    // ---- segmented xout: boundary-last lane sums its segment, 3 atomics per segment ----
    if (t < EDG) {
        const bool last = (t == EDG - 1) || (ssrc[t + 1] != ssrc[t]);
        if (last) {
            const int s = ssrc[t];
            float ax = 0.f, ay = 0.f, az = 0.f;
            int j = t;
            while (j >= 0 && ssrc[j] == s) {
                ax += sPart[0][j]; ay += sPart[1][j]; az += sPart[2][j];
                --j;
            }
            atom_add_f32(&xout[3 * s + 0], ax);
            atom_add_f32(&xout[3 * s + 1], ay);
            atom_add_f32(&xout[3 * s + 2], az);
        }
    }
}

// ---------------- node ----------------
__global__ __launch_bounds__(256, 4) void node_kernel(
    const float* __restrict__ h, const ushort_t* __restrict__ hb,
    const ushort_t* __restrict__ maggr,
    const ushort_t* __restrict__ n1b, const float* __restrict__ nb1,
    const ushort_t* __restrict__ n2b, const float* __restrict__ nb2,
    const ushort_t* __restrict__ n3b, const float* __restrict__ nb3,
    float* __restrict__ hout) {
    __shared__ ushort_t sE[16384];
    const int t = threadIdx.x;
    const int lane = t & 63;
    const int wid = t >> 6;
    const int r15 = lane & 15;
    const int khi = lane >> 4;
    const int rhi = khi * 4;
    const int fb = wid * 32;
    const int n0 = blockIdx.x * 64;

    // stage [hb[n] | maggr[n]] (raw bf16, 16B chunks)
    const uint4* hb4 = (const uint4*)hb;
    const uint4* mg4 = (const uint4*)maggr;
#pragma unroll
    for (int it = 0; it < 8; ++it) {
        const int idx = it * 256 + t;
        const int e = idx >> 5, c = idx & 31;
        const int n = n0 + e;
        uint4 v = make_uint4(0u, 0u, 0u, 0u);
        if (n < N_NODES) v = (c < 16) ? hb4[(size_t)n * 16 + c] : mg4[(size_t)n * 16 + (c - 16)];
        const int ui = (e * 256 + c * 8) ^ ((e & 7) << 3);
        *(uint4*)(sE + ui) = v;
    }
    __syncthreads();

    // N1: K=256, wave owns 32 feats (2 row-blocks)
    f32x4 acc[2][4];
#pragma unroll
    for (int mi = 0; mi < 2; ++mi)
#pragma unroll
        for (int ni = 0; ni < 4; ++ni) acc[mi][ni] = (f32x4){0.f, 0.f, 0.f, 0.f};
#pragma unroll
    for (int ks = 0; ks < 8; ++ks) {
        const bf16x8 a0 = *(const bf16x8*)(n1b + (fb + r15) * 256 + ks * 32 + khi * 8);
        const bf16x8 a1 = *(const bf16x8*)(n1b + (fb + 16 + r15) * 256 + ks * 32 + khi * 8);
        bf16x8 b[4];
#pragma unroll
        for (int ni = 0; ni < 4; ++ni) {
            const int edge = ni * 16 + r15;
            const int ui = (edge * 256 + ks * 32 + khi * 8) ^ ((edge & 7) << 3);
            b[ni] = *(const bf16x8*)(sE + ui);
        }
#pragma unroll
        for (int ni = 0; ni < 4; ++ni) {
            acc[0][ni] = __builtin_amdgcn_mfma_f32_16x16x32_bf16(a0, b[ni], acc[0][ni], 0, 0, 0);
            acc[1][ni] = __builtin_amdgcn_mfma_f32_16x16x32_bf16(a1, b[ni], acc[1][ni], 0, 0, 0);
        }
    }
    __syncthreads();
    {
        const float4 bb0 = *(const float4*)&nb1[fb + rhi];
        const float4 bb1 = *(const float4*)&nb1[fb + 16 + rhi];
#pragma unroll
        for (int mi = 0; mi < 2; ++mi) {
            const float4 bb = mi ? bb1 : bb0;
#pragma unroll
            for (int ni = 0; ni < 4; ++ni) {
                const int edge = ni * 16 + r15;
                const float v0 = silu_f(acc[mi][ni][0] + bb.x);
                const float v1 = silu_f(acc[mi][ni][1] + bb.y);
                const float v2 = silu_f(acc[mi][ni][2] + bb.z);
                const float v3 = silu_f(acc[mi][ni][3] + bb.w);
                const int ui = (edge * 128 + fb + mi * 16 + rhi) ^ ((edge & 7) << 3);
                *(uint2*)(sE + ui) = make_uint2(pack2(v0, v1), pack2(v2, v3));
            }
        }
    }
    __syncthreads();

    // N2: two 16-feat halves; b[4] loaded before MFMAs
    {
#pragma unroll
        for (int half = 0; half < 2; ++half) {
            f32x4 a2[4];
#pragma unroll
            for (int ni = 0; ni < 4; ++ni) a2[ni] = (f32x4){0.f, 0.f, 0.f, 0.f};
            const int fbh = fb + half * 16;
#pragma unroll
            for (int ks = 0; ks < 4; ++ks) {
                const bf16x8 a0 = *(const bf16x8*)(n2b + (fbh + r15) * 128 + ks * 32 + khi * 8);
                bf16x8 b[4];
#pragma unroll
                for (int ni = 0; ni < 4; ++ni) {
                    const int edge = ni * 16 + r15;
                    const int ui = (edge * 128 + ks * 32 + khi * 8) ^ ((edge & 7) << 3);
                    b[ni] = *(const bf16x8*)(sE + ui);
                }
#pragma unroll
                for (int ni = 0; ni < 4; ++ni)
                    a2[ni] = __builtin_amdgcn_mfma_f32_16x16x32_bf16(a0, b[ni], a2[ni], 0, 0, 0);
            }
            const float4 bb = *(const float4*)&nb2[fbh + rhi];
#pragma unroll
            for (int ni = 0; ni < 4; ++ni) {
                const int edge = ni * 16 + r15;
                const float v0 = silu_f(a2[ni][0] + bb.x);
                const float v1 = silu_f(a2[ni][1] + bb.y);
                const float v2 = silu_f(a2[ni][2] + bb.z);
                const float v3 = silu_f(a2[ni][3] + bb.w);
                const int ui = (8192 + edge * 128 + fbh + rhi) ^ ((edge & 7) << 3);
                *(uint2*)(sE + ui) = make_uint2(pack2(v0, v1), pack2(v2, v3));
            }
        }
    }
    __syncthreads();

    // N3 + residual epilogue straight to global (f32, float4 stores)
    {
        f32x4 a3[2][4];
#pragma unroll
        for (int mi = 0; mi < 2; ++mi)
#pragma unroll
            for (int ni = 0; ni < 4; ++ni) a3[mi][ni] = (f32x4){0.f, 0.f, 0.f, 0.f};
#pragma unroll
        for (int ks = 0; ks < 4; ++ks) {
            const bf16x8 a0 = *(const bf16x8*)(n3b + (fb + r15) * 128 + ks * 32 + khi * 8);
            const bf16x8 a1 = *(const bf16x8*)(n3b + (fb + 16 + r15) * 128 + ks * 32 + khi * 8);
            bf16x8 b[4];
#pragma unroll
            for (int ni = 0; ni < 4; ++ni) {
                const int edge = ni * 16 + r15;
                const int ui = (8192 + edge * 128 + ks * 32 + khi * 8) ^ ((edge & 7) << 3);
                b[ni] = *(const bf16x8*)(sE + ui);
            }
#pragma unroll
            for (int ni = 0; ni < 4; ++ni) {
                a3[0][ni] = __builtin_amdgcn_mfma_f32_16x16x32_bf16(a0, b[ni], a3[0][ni], 0, 0, 0);
                a3[1][ni] = __builtin_amdgcn_mfma_f32_16x16x32_bf16(a1, b[ni], a3[1][ni], 0, 0, 0);
            }
        }
        const float4 bb0 = *(const float4*)&nb3[fb + rhi];
        const float4 bb1 = *(const float4*)&nb3[fb + 16 + rhi];
#pragma unroll
        for (int mi = 0; mi < 2; ++mi) {
            const float4 bb = mi ? bb1 : bb0;
#pragma unroll
            for (int ni = 0; ni < 4; ++ni) {
                const int n = n0 + ni * 16 + r15;
                if (n < N_NODES) {
                    const size_t o = (size_t)n * 128 + fb + mi * 16 + rhi;
                    const float4 hv = *(const float4*)&h[o];
                    float4 ov;
                    ov.x = hv.x + a3[mi][ni][0] + bb.x;
                    ov.y = hv.y + a3[mi][ni][1] + bb.y;
                    ov.z = hv.z + a3[mi][ni][2] + bb.z;
                    ov.w = hv.w + a3[mi][ni][3] + bb.w;
                    *(float4*)&hout[o] = ov;
                }
            }
        }
    }
}

extern "C" void kernel_launch(void* const* d_in, const int* in_sizes, int n_in,
                              void* d_out, int out_size, void* d_ws, size_t ws_size,
                              hipStream_t stream) {
    const float* x   = (const float*)d_in[0];
    const float* h   = (const float*)d_in[1];
    const int*   ei  = (const int*)d_in[2];
    const float* ew1 = (const float*)d_in[3];
    const float* eb1 = (const float*)d_in[4];
    const float* ew2 = (const float*)d_in[5];
    const float* eb2 = (const float*)d_in[6];
    const float* ew3 = (const float*)d_in[7];
    const float* eb3 = (const float*)d_in[8];
    const float* cw1 = (const float*)d_in[9];
    const float* cb1 = (const float*)d_in[10];
    const float* cw2 = (const float*)d_in[11];
    const float* cb2 = (const float*)d_in[12];
    const float* nw1 = (const float*)d_in[13];
    const float* nb1 = (const float*)d_in[14];
    const float* nw2 = (const float*)d_in[15];
    const float* nb2 = (const float*)d_in[16];
    const float* nw3 = (const float*)d_in[17];
    const float* nb3 = (const float*)d_in[18];

    float* out  = (float*)d_out;
    float* xout = out;                       // [50000,3]
    float* hout = out + (size_t)N_NODES * 3; // [50000,128]
    ushort_t* wsu = (ushort_t*)d_ws;

    ushort_t* maggr = wsu + U_MAGGR;
    const ushort_t* hb  = wsu + U_HB;
    const ushort_t* wab = wsu + U_W1B;       // Wab 256x128
    const ushort_t* w2b = wsu + U_W2B;
    const ushort_t* w3b = wsu + U_W3B;
    const ushort_t* c1b = wsu + U_C1B;
    const ushort_t* n1b = wsu + U_N1B;
    const ushort_t* n2b = wsu + U_N2B;
    const ushort_t* n3b = wsu + U_N3B;
    const float* w1d2 = (const float*)(wsu + U_W1D2);
    ushort_t* wcb = wsu + U_WC;
    float* bcv = (float*)(wsu + U_BC);
    int2* sd = (int2*)(wsu + U_SD);
    unsigned int* cnt = (unsigned int*)(wsu + U_CNT);
    unsigned int* ptr = (unsigned int*)(wsu + U_PTR);

    // AB table (bf16 [N][256] = 25.6 MB) stashed in the hout region of d_out;
    // node_kernel fully overwrites hout afterwards.
    ushort_t* abp = (ushort_t*)hout;

    hipMemsetAsync(cnt, 0, 50048 * sizeof(unsigned int), stream);

    const long prep_total = 800000L + 800000L + 32768 + 3 * 16384 + 32768 + 2 * 16384 + 128 + 37500 + N_EDGES;
    const int prep_blocks = (int)((prep_total + 255) / 256);
    prep_kernel<<<prep_blocks, 256, 0, stream>>>(x, h, ew1, ew2, ew3, cw1, nw1, nw2, nw3,
                                                 ei, wsu, xout);

    scan_kernel<<<1, 1024, 0, stream>>>(cnt, ptr);

    const int nAB = (N_NODES + 63) / 64;     // 782; block nAB = Wc; blocks nAB+1.. = scatter
    const int nSC = (N_EDGES + 255) / 256;   // 2500 scatter blocks
    abscatter_kernel<<<nAB + 1 + nSC, 256, 0, stream>>>(hb, wab, eb1, abp,
                                                        c1b, ew3, eb3, cb1, wcb, bcv,
                                                        ei, ptr, sd, nAB);

    edge_kernel<<<N_EDGES / EDG, 512, 0, stream>>>(x, abp, sd,
                                                   w1d2, w2b, eb2, w3b, eb3,
                                                   wcb, bcv, cw2, cb2,
                                                   xout, maggr);

    node_kernel<<<(N_NODES + 63) / 64, 256, 0, stream>>>(h, hb, maggr,
                                                         n1b, nb1, n2b, nb2, n3b, nb3,
                                                         hout);
}

// Round 7
// 292.041 us; speedup vs baseline: 1.3712x; 1.3712x over previous
//
#include <hip/hip_runtime.h>
#include <hip/hip_bf16.h>

#define N_NODES 50000
#define N_EDGES 640000
#define HID 128
#define EDG 128          // edges per edge-block

typedef unsigned short ushort_t;
typedef __attribute__((ext_vector_type(8))) short bf16x8;   // 8 bf16 = 4 VGPR (MFMA A/B frag)
typedef __attribute__((ext_vector_type(4))) float f32x4;    // MFMA C/D frag

// ws layout (ushort units from base):
//   maggr  [0,        6400000)   bf16 N x 128 (pk-atomic accumulated)
//   hb     [6400000, 12800000)   bf16 N x 128 (h pre-converted)
//   w1b    [12800000,12832768)   Wab 256 x 128: rows 0..127 = ew1[:,0:128] (A), rows 128..255 = ew1[:,128:256] (B)
//   w2b    [12832768,12849152)   128 x 128
//   w3b    [12849152,12865536)   128 x 128
//   c1b    [12865536,12881920)   128 x 128 (bf16 cw1; consumed by wc block)
//   n1b    [12881920,12914688)   128 x 256
//   n2b    [12914688,12931072)   128 x 128
//   n3b    [12931072,12947456)   128 x 128
//   w1d2   (float*) at ushort 12947456, 128 f32 = ew1[:,256]
//   wcb    [12947712,12964096)   128 x 128 bf16 = Wc1 @ W3 (composed coord weight)
//   bc     (float*) at ushort 12964096, 128 f32 = Wc1 @ eb3 + cb1
//   sd     [12964352,15524352)   int2[640000] src-sorted (src,dst) pairs
//   cnt    [15524352,15624448)   u32[50048]  per-src degree histogram
//   ptr    [15624448,15724544)   u32[50048]  exclusive scan of cnt
//   rank   [15724544,17004544)   u32[640000] per-edge rank within its src group
// AB table (bf16 N x 256 = 25.6 MB) lives in d_out's hout region (dead until node_kernel
// fully overwrites it): A[n] = h@W1a^T in feats 0..127, B[n] = h@W1b^T + eb1 in feats 128..255.
#define U_MAGGR 0
#define U_HB    6400000
#define U_W1B   12800000
#define U_W2B   12832768
#define U_W3B   12849152
#define U_C1B   12865536
#define U_N1B   12881920
#define U_N2B   12914688
#define U_N3B   12931072
#define U_W1D2  12947456
#define U_WC    12947712
#define U_BC    12964096
#define U_SD    12964352
#define U_CNT   15524352
#define U_PTR   15624448
#define U_RANK  15724544

// silu via exp2 + fast rcp (bf16-output tolerance; saves div fixup sequence)
__device__ __forceinline__ float silu_f(float v) {
    const float e = __builtin_amdgcn_exp2f(v * -1.442695041f);
    return v * __builtin_amdgcn_rcpf(1.0f + e);
}

__device__ __forceinline__ ushort_t f2b(float f) {
    __hip_bfloat16 b = __float2bfloat16(f);          // RNE
    return __builtin_bit_cast(ushort_t, b);
}
__device__ __forceinline__ float b2f(ushort_t u) {
    union { float f; unsigned int i; } v; v.i = ((unsigned int)u) << 16; return v.f;
}
__device__ __forceinline__ float u2f(unsigned int u) {
    union { float f; unsigned int i; } v; v.i = u; return v.f;
}
__device__ __forceinline__ unsigned int pack2(float a, float b) {
    return (unsigned int)f2b(a) | ((unsigned int)f2b(b) << 16);
}
// uint4 of 8 bf16 -> 8 f32 (1 VALU op each: shl or and)
__device__ __forceinline__ void up8(const uint4& u, float* f) {
    f[0] = u2f(u.x << 16); f[1] = u2f(u.x & 0xffff0000u);
    f[2] = u2f(u.y << 16); f[3] = u2f(u.y & 0xffff0000u);
    f[4] = u2f(u.z << 16); f[5] = u2f(u.z & 0xffff0000u);
    f[6] = u2f(u.w << 16); f[7] = u2f(u.w & 0xffff0000u);
}
__device__ __forceinline__ void atom_add_f32(float* p, float v) { unsafeAtomicAdd(p, v); }

// packed bf16x2 atomic add (gfx950: global_atomic_pk_add_bf16)
__device__ __forceinline__ void atom_pk_bf16(ushort_t* p, unsigned int v) {
#if __has_builtin(__builtin_amdgcn_global_atomic_fadd_v2bf16)
    typedef __attribute__((ext_vector_type(2))) short s2;
    s2 sv = __builtin_bit_cast(s2, v);
    __builtin_amdgcn_global_atomic_fadd_v2bf16((__attribute__((address_space(1))) s2*)p, sv);
#else
    unsigned int* up = (unsigned int*)p;
    unsigned int old = __hip_atomic_load(up, __ATOMIC_RELAXED, __HIP_MEMORY_SCOPE_AGENT), assumed;
    do {
        assumed = old;
        float lo = b2f((ushort_t)(assumed & 0xffff)) + b2f((ushort_t)(v & 0xffff));
        float hi = b2f((ushort_t)(assumed >> 16)) + b2f((ushort_t)(v >> 16));
        unsigned int nv = (unsigned int)f2b(lo) | ((unsigned int)f2b(hi) << 16);
        old = atomicCAS(up, assumed, nv);
    } while (old != assumed);
#endif
}

// ---------------- prep (vectorized; hist also records per-edge rank; cnt pre-zeroed) ----------------
__global__ void prep_kernel(const float* __restrict__ x, const float* __restrict__ h,
                            const float* __restrict__ ew1, const float* __restrict__ ew2,
                            const float* __restrict__ ew3, const float* __restrict__ cw1,
                            const float* __restrict__ nw1, const float* __restrict__ nw2,
                            const float* __restrict__ nw3, const int* __restrict__ ei,
                            ushort_t* __restrict__ wsu, float* __restrict__ xout) {
    long i = (long)blockIdx.x * 256 + threadIdx.x;
    if (i < 800000) {   // maggr zero, 16B stores
        ((uint4*)(wsu + U_MAGGR))[i] = make_uint4(0u, 0u, 0u, 0u);
        return;
    }
    i -= 800000;
    if (i < 800000) {   // h -> bf16, 8 floats per thread
        const float4* h4 = (const float4*)h;
        const float4 f0 = h4[2 * i], f1 = h4[2 * i + 1];
        ((uint4*)(wsu + U_HB))[i] = make_uint4(pack2(f0.x, f0.y), pack2(f0.z, f0.w),
                                               pack2(f1.x, f1.y), pack2(f1.z, f1.w));
        return;
    }
    i -= 800000;
    if (i < 32768) {
        // Wab[f][k]: f<128 -> ew1[f][k] (A half), f>=128 -> ew1[f-128][128+k] (B half)
        const int f = (int)(i >> 7);
        const int k = (int)(i & 127);
        const int src = (f < 128) ? (f * 257 + k) : ((f - 128) * 257 + 128 + k);
        wsu[U_W1B + i] = f2b(ew1[src]);
        return;
    }
    i -= 32768;
    if (i < 16384) { wsu[U_W2B + i] = f2b(ew2[i]); return; }
    i -= 16384;
    if (i < 16384) { wsu[U_W3B + i] = f2b(ew3[i]); return; }
    i -= 16384;
    if (i < 16384) { wsu[U_C1B + i] = f2b(cw1[i]); return; }
    i -= 16384;
    if (i < 32768) { wsu[U_N1B + i] = f2b(nw1[i]); return; }
    i -= 32768;
    if (i < 16384) { wsu[U_N2B + i] = f2b(nw2[i]); return; }
    i -= 16384;
    if (i < 16384) { wsu[U_N3B + i] = f2b(nw3[i]); return; }
    i -= 16384;
    if (i < 128) { ((float*)(wsu + U_W1D2))[i] = ew1[i * 257 + 256]; return; }
    i -= 128;
    if (i < 37500) { ((float4*)xout)[i] = ((const float4*)x)[i]; return; }
    i -= 37500;
    if (i < N_EDGES) {
        const unsigned int r = atomicAdd(((unsigned int*)(wsu + U_CNT)) + ei[i], 1u);
        ((unsigned int*)(wsu + U_RANK))[i] = r;
    }
}

// ---------------- counting-sort scatter, atomic-free: pos = ptr[s] + rank[e] ----------------
__global__ void scatter_kernel(const int* __restrict__ ei, const unsigned int* __restrict__ ptr,
                               const unsigned int* __restrict__ rank, int2* __restrict__ sd) {
    const int e = blockIdx.x * 256 + threadIdx.x;
    if (e >= N_EDGES) return;
    const int s = ei[e], d = ei[N_EDGES + e];
    const unsigned int pos = ptr[s] + rank[e];
    sd[pos] = make_int2(s, d);
}

// ---------------- AB precompute + Wc compose + scan (extra blocks) ----------------
// Blocks 0..nAB-1: AB[n] = [h@W1a^T | h@W1b^T + eb1]   (64 nodes/block, 4 waves)
// Block nAB:       Wc = Wc1 @ W3 (bf16) and bc = Wc1 @ eb3 + cb1
// Block nAB+1:     exclusive scan cnt -> ptr (parallel, hidden under AB blocks)
__global__ __launch_bounds__(256, 4) void ab_kernel(
    const ushort_t* __restrict__ hb, const ushort_t* __restrict__ wab,
    const float* __restrict__ eb1, ushort_t* __restrict__ abp,
    const ushort_t* __restrict__ c1b, const float* __restrict__ ew3,
    const float* __restrict__ eb3, const float* __restrict__ cb1,
    ushort_t* __restrict__ wcb, float* __restrict__ bcv,
    const unsigned int* __restrict__ cnt, unsigned int* __restrict__ ptr, int nAB) {
    __shared__ ushort_t sH[16384];   // AB path uses first 8192; Wc block uses all 32 KB
    const int t = threadIdx.x;
    const int lane = t & 63;
    const int wid = t >> 6;          // 0..3
    const int r15 = lane & 15;
    const int khi = lane >> 4;
    const int rhi = khi * 4;

    if ((int)blockIdx.x == nAB + 1) {
        // ---- parallel exclusive scan of cnt[50000] -> ptr ----
        __shared__ unsigned int sSum[256];
        const int lo = t * 196;
        const int hi = (lo + 196 < N_NODES) ? lo + 196 : N_NODES;
        unsigned int s = 0;
#pragma unroll 4
        for (int i = lo; i < hi; ++i) s += cnt[i];
        sSum[t] = s;
        __syncthreads();
#pragma unroll
        for (int off = 1; off < 256; off <<= 1) {
            const unsigned int v = (t >= off) ? sSum[t - off] : 0u;
            __syncthreads();
            sSum[t] += v;
            __syncthreads();
        }
        unsigned int run = (t == 0) ? 0u : sSum[t - 1];
#pragma unroll 4
        for (int i = lo; i < hi; ++i) { const unsigned int c = cnt[i]; ptr[i] = run; run += c; }
        return;
    }

    if ((int)blockIdx.x == nAB) {
        // ---- stage Bt[k][m] = ew3[m][k] bf16, XOR-swizzled ----
        for (int i = t; i < 16384; i += 256) {
            const int m = i >> 7, k = i & 127;
            sH[(k * 128 + m) ^ ((k & 7) << 3)] = f2b(ew3[i]);
        }
        __syncthreads();
        // ---- Wc[f][k] = sum_m Wc1[f][m] * W3[m][k] ----
#pragma unroll
        for (int kh = 0; kh < 2; ++kh) {
#pragma unroll
            for (int fi = 0; fi < 2; ++fi) {
                const int f0 = wid * 32 + fi * 16;
                const int kc = kh * 64;
                f32x4 acc[4];
#pragma unroll
                for (int ni = 0; ni < 4; ++ni) acc[ni] = (f32x4){0.f, 0.f, 0.f, 0.f};
#pragma unroll
                for (int ks = 0; ks < 4; ++ks) {
                    const bf16x8 a0 = *(const bf16x8*)(c1b + (f0 + r15) * 128 + ks * 32 + khi * 8);
                    bf16x8 b[4];
#pragma unroll
                    for (int ni = 0; ni < 4; ++ni) {
                        const int kk = kc + ni * 16 + r15;
                        b[ni] = *(const bf16x8*)(sH + ((kk * 128 + ks * 32 + khi * 8) ^ ((kk & 7) << 3)));
                    }
#pragma unroll
                    for (int ni = 0; ni < 4; ++ni)
                        acc[ni] = __builtin_amdgcn_mfma_f32_16x16x32_bf16(a0, b[ni], acc[ni], 0, 0, 0);
                }
#pragma unroll
                for (int ni = 0; ni < 4; ++ni) {
                    const int kk = kc + ni * 16 + r15;
#pragma unroll
                    for (int j = 0; j < 4; ++j)
                        wcb[(f0 + rhi + j) * 128 + kk] = f2b(acc[ni][j]);
                }
            }
        }
        // ---- bc[f] = cb1[f] + sum_m Wc1[f][m] * eb3[m] ----
        {
            const int f = t >> 1, hf = t & 1;
            float s = 0.f;
            const int m0 = hf * 64;
#pragma unroll 8
            for (int m = m0; m < m0 + 64; ++m)
                s = fmaf(b2f(c1b[f * 128 + m]), eb3[m], s);
            s += __shfl_xor(s, 1);
            if (hf == 0) bcv[f] = cb1[f] + s;
        }
        return;
    }

    const int fb = wid * 64;         // 64 feats per wave (4 row-blocks)
    const int n0 = blockIdx.x * 64;

    const uint4* hb4 = (const uint4*)hb;
#pragma unroll
    for (int it = 0; it < 4; ++it) {
        const int idx = it * 256 + t;          // 1024 tasks: 64 nodes x 16 chunks
        const int e = idx >> 4, c = idx & 15;
        const int n = n0 + e;
        uint4 v = make_uint4(0u, 0u, 0u, 0u);
        if (n < N_NODES) v = hb4[(size_t)n * 16 + c];
        const int ui = (e * 128 + c * 8) ^ ((e & 7) << 3);
        *(uint4*)(sH + ui) = v;
    }
    __syncthreads();

    f32x4 acc[4][4];
#pragma unroll
    for (int mi = 0; mi < 4; ++mi)
#pragma unroll
        for (int ni = 0; ni < 4; ++ni) acc[mi][ni] = (f32x4){0.f, 0.f, 0.f, 0.f};
#pragma unroll
    for (int ks = 0; ks < 4; ++ks) {
        bf16x8 a[4];
#pragma unroll
        for (int mi = 0; mi < 4; ++mi)
            a[mi] = *(const bf16x8*)(wab + (fb + mi * 16 + r15) * 128 + ks * 32 + khi * 8);
        bf16x8 b[4];
#pragma unroll
        for (int ni = 0; ni < 4; ++ni) {
            const int e = ni * 16 + r15;
            const int ui = (e * 128 + ks * 32 + khi * 8) ^ ((e & 7) << 3);
            b[ni] = *(const bf16x8*)(sH + ui);
        }
#pragma unroll
        for (int mi = 0; mi < 4; ++mi)
#pragma unroll
            for (int ni = 0; ni < 4; ++ni)
                acc[mi][ni] = __builtin_amdgcn_mfma_f32_16x16x32_bf16(a[mi], b[ni], acc[mi][ni], 0, 0, 0);
    }

#pragma unroll
    for (int mi = 0; mi < 4; ++mi) {
        const int f0 = fb + mi * 16 + rhi;     // entire 16-block is on one side of 128
        float4 bb = make_float4(0.f, 0.f, 0.f, 0.f);
        if (f0 >= 128) bb = *(const float4*)&eb1[f0 - 128];
#pragma unroll
        for (int ni = 0; ni < 4; ++ni) {
            const int n = n0 + ni * 16 + r15;
            if (n < N_NODES) {
                *(uint2*)(abp + (size_t)n * 256 + f0) =
                    make_uint2(pack2(acc[mi][ni][0] + bb.x, acc[mi][ni][1] + bb.y),
                               pack2(acc[mi][ni][2] + bb.z, acc[mi][ni][3] + bb.w));
            }
        }
    }
}

// swapped dense layer, K=128: D[feat][edge] = W(128x128) x act^T.
// 8 waves: wave wid owns 16 output feats x NE*16 edges.
// src rows: [NE*16 edges][128 ushorts], XOR-swizzled ^((edge&7)<<3) (ushort units).
template <bool ACT, int NE>
__device__ __forceinline__ void dense128(ushort_t* sE, int srcBase, int dstBase,
                                         const ushort_t* __restrict__ W,
                                         const float* __restrict__ bias,
                                         int r15, int khi, int rhi, int fb) {
    f32x4 acc[NE];
#pragma unroll
    for (int ni = 0; ni < NE; ++ni) acc[ni] = (f32x4){0.f, 0.f, 0.f, 0.f};
#pragma unroll
    for (int ks = 0; ks < 4; ++ks) {
        const bf16x8 a0 = *(const bf16x8*)(W + (fb + r15) * 128 + ks * 32 + khi * 8);
        bf16x8 b[NE];
#pragma unroll
        for (int ni = 0; ni < NE; ++ni) {
            const int edge = ni * 16 + r15;
            const int ui = (srcBase + edge * 128 + ks * 32 + khi * 8) ^ ((edge & 7) << 3);
            b[ni] = *(const bf16x8*)(sE + ui);
        }
#pragma unroll
        for (int ni = 0; ni < NE; ++ni)
            acc[ni] = __builtin_amdgcn_mfma_f32_16x16x32_bf16(a0, b[ni], acc[ni], 0, 0, 0);
    }
    const float4 bb = *(const float4*)&bias[fb + rhi];
#pragma unroll
    for (int ni = 0; ni < NE; ++ni) {
        const int edge = ni * 16 + r15;
        float v0 = acc[ni][0] + bb.x;
        float v1 = acc[ni][1] + bb.y;
        float v2 = acc[ni][2] + bb.z;
        float v3 = acc[ni][3] + bb.w;
        if (ACT) { v0 = silu_f(v0); v1 = silu_f(v1); v2 = silu_f(v2); v3 = silu_f(v3); }
        const int ui = (dstBase + edge * 128 + fb + rhi) ^ ((edge & 7) << 3);
        *(uint2*)(sE + ui) = make_uint2(pack2(v0, v1), pack2(v2, v3));
    }
}

// ---------------- edge ----------------
// 512 threads / 8 waves per block, 128 src-sorted edges per block (2 blocks/CU).
// Phases: P0 gather-issue+meta | P1 act1 stage | P2 w2 | P3 w3->LDS + c1'(composed)->dot
//         P4 segmented aggr (f32 partials -> ~1 atomic per segment) + segmented xout
__global__ __launch_bounds__(512, 4) void edge_kernel(
    const float* __restrict__ x, const ushort_t* __restrict__ ab,
    const int2* __restrict__ sd,
    const float* __restrict__ w1d2,
    const ushort_t* __restrict__ w2b, const float* __restrict__ eb2,
    const ushort_t* __restrict__ w3b, const float* __restrict__ eb3,
    const ushort_t* __restrict__ wcb, const float* __restrict__ bcv,
    const float* __restrict__ cw2, const float* __restrict__ cb2,
    float* __restrict__ xout, ushort_t* __restrict__ maggr) {
    __shared__ ushort_t sE[32768];   // 64 KB: act1/m_ij @0, act2 @16384 ([128][128] each)
    __shared__ float srel[EDG][3];
    __shared__ float sd2[EDG];
    __shared__ int ssrc[EDG];
    __shared__ float sPart[8][EDG];  // wave partials; rows 0..2 reused as xout contributions

    const int t = threadIdx.x;
    const int lane = t & 63;
    const int wid = t >> 6;          // 0..7
    const int r15 = lane & 15;
    const int khi = lane >> 4;       // 0..3
    const int rhi = khi * 4;
    const int fb = wid * 16;         // 16 feats per wave
    const int e0 = blockIdx.x * EDG;

    // ---- P0: issue AB gathers; c = t&15 is iteration-invariant, e = it*32 + (t>>4).
    //          t<EDG concurrently builds srel/sd2/ssrc.
    uint4 va[4], vb[4];
    const int c = t & 15;
    const int ebase = t >> 4;        // 0..31
    {
        const uint4* ab4 = (const uint4*)ab;
#pragma unroll
        for (int it = 0; it < 4; ++it) {
            const int e = it * 32 + ebase;
            const int2 p = sd[e0 + e];
            va[it] = ab4[(size_t)p.x * 32 + c];         // A half of AB[src]
            vb[it] = ab4[(size_t)p.y * 32 + 16 + c];    // B half of AB[dst]
        }
    }
    if (t < EDG) {
        const int2 p = sd[e0 + t];
        ssrc[t] = p.x;
        const float rx = x[3 * p.x] - x[3 * p.y];
        const float ry = x[3 * p.x + 1] - x[3 * p.y + 1];
        const float rz = x[3 * p.x + 2] - x[3 * p.y + 2];
        srel[t][0] = rx; srel[t][1] = ry; srel[t][2] = rz;
        sd2[t] = rx * rx + ry * ry + rz * rz;
    }
    __syncthreads();

    // ---- P1: act1 = silu(A[src] + B[dst] + d2*w1d2); w1d2 loads hoisted (c fixed) ----
    {
        const float4 w0 = *(const float4*)&w1d2[c * 8];
        const float4 w1 = *(const float4*)&w1d2[c * 8 + 4];
#pragma unroll
        for (int it = 0; it < 4; ++it) {
            const int e = it * 32 + ebase;
            const float d2 = sd2[e];
            float fa[8], fbv[8];
            up8(va[it], fa);
            up8(vb[it], fbv);
            const float v0 = silu_f(fmaf(d2, w0.x, fa[0] + fbv[0]));
            const float v1 = silu_f(fmaf(d2, w0.y, fa[1] + fbv[1]));
            const float v2 = silu_f(fmaf(d2, w0.z, fa[2] + fbv[2]));
            const float v3 = silu_f(fmaf(d2, w0.w, fa[3] + fbv[3]));
            const float v4 = silu_f(fmaf(d2, w1.x, fa[4] + fbv[4]));
            const float v5 = silu_f(fmaf(d2, w1.y, fa[5] + fbv[5]));
            const float v6 = silu_f(fmaf(d2, w1.z, fa[6] + fbv[6]));
            const float v7 = silu_f(fmaf(d2, w1.w, fa[7] + fbv[7]));
            uint4 st;
            st.x = pack2(v0, v1); st.y = pack2(v2, v3);
            st.z = pack2(v4, v5); st.w = pack2(v6, v7);
            *(uint4*)(sE + ((e * 128 + c * 8) ^ ((e & 7) << 3))) = st;
        }
    }
    __syncthreads();

    // ---- P2: w2 dense: act1 -> silu -> act2 @16384 ----
    dense128<true, EDG / 16>(sE, 0, 16384, w2b, eb2, r15, khi, rhi, fb);
    __syncthreads();

    // ---- P3a: w3 dense: act2 -> m_ij @0 (packed LDS store) ----
    dense128<false, EDG / 16>(sE, 16384, 0, w3b, eb3, r15, khi, rhi, fb);

    // ---- P3b: c1' dense with composed Wc (reads act2 directly) -> silu -> dot(cw2) ----
    {
        f32x4 acc[EDG / 16];
#pragma unroll
        for (int ni = 0; ni < EDG / 16; ++ni) acc[ni] = (f32x4){0.f, 0.f, 0.f, 0.f};
#pragma unroll
        for (int ks = 0; ks < 4; ++ks) {
            const bf16x8 a0 = *(const bf16x8*)(wcb + (fb + r15) * 128 + ks * 32 + khi * 8);
            bf16x8 b[EDG / 16];
#pragma unroll
            for (int ni = 0; ni < EDG / 16; ++ni) {
                const int edge = ni * 16 + r15;
                const int u = (16384 + edge * 128 + ks * 32 + khi * 8) ^ ((edge & 7) << 3);
                b[ni] = *(const bf16x8*)(sE + u);
            }
#pragma unroll
            for (int ni = 0; ni < EDG / 16; ++ni)
                acc[ni] = __builtin_amdgcn_mfma_f32_16x16x32_bf16(a0, b[ni], acc[ni], 0, 0, 0);
        }
        const float4 bb = *(const float4*)&bcv[fb + rhi];
        const float4 cw = *(const float4*)&cw2[fb + rhi];
        float p[EDG / 16];
#pragma unroll
        for (int ni = 0; ni < EDG / 16; ++ni) {
            float s = silu_f(acc[ni][0] + bb.x) * cw.x;
            s = fmaf(silu_f(acc[ni][1] + bb.y), cw.y, s);
            s = fmaf(silu_f(acc[ni][2] + bb.z), cw.z, s);
            s = fmaf(silu_f(acc[ni][3] + bb.w), cw.w, s);
            p[ni] = s;
        }
#pragma unroll
        for (int ni = 0; ni < EDG / 16; ++ni) {
            p[ni] += __shfl_xor(p[ni], 16);
            p[ni] += __shfl_xor(p[ni], 32);
        }
        if (khi == 0) {
#pragma unroll
            for (int ni = 0; ni < EDG / 16; ++ni) sPart[wid][ni * 16 + r15] = p[ni];
        }
    }
    __syncthreads();

    // coef + per-edge xout contributions into sPart rows 0..2 (column-private)
    if (t < EDG) {
        float s = sPart[0][t];
#pragma unroll
        for (int w = 1; w < 8; ++w) s += sPart[w][t];
        const float coef = tanhf(s + cb2[0]);
        sPart[0][t] = srel[t][0] * coef;
        sPart[1][t] = srel[t][1] * coef;
        sPart[2][t] = srel[t][2] * coef;
    }

    // ---- P4: segmented maggr aggregation. thread = (dw 0..63, strip 0..7), 16 edges/strip;
    //          f32 partials per src-segment, one pk-atomic per boundary. Wave-uniform branches.
    {
        const int dw = t & 63;
        const int rs = t >> 6;
        float lo = 0.f, hi = 0.f;
        int cur = ssrc[rs * 16];
#pragma unroll
        for (int j = 0; j < 16; ++j) {
            const int e = rs * 16 + j;
            const int s = ssrc[e];
            if (s != cur) {
                atom_pk_bf16(maggr + (size_t)cur * 128 + dw * 2, pack2(lo, hi));
                lo = 0.f; hi = 0.f; cur = s;
            }
            const unsigned int v = *(const unsigned int*)(sE + ((e * 128 + dw * 2) ^ ((e & 7) << 3)));
            lo += b2f((ushort_t)(v & 0xffff));
            hi += b2f((ushort_t)(v >> 16));
        }
        atom_pk_bf16(maggr + (size_t)cur * 128 + dw * 2, pack2(lo, hi));
    }
    __syncthreads();

    // ---- segmented xout: boundary-last lane sums its segment, 3 atomics per segment ----
    if (t < EDG) {
        const bool last = (t == EDG - 1) || (ssrc[t + 1] != ssrc[t]);
        if (last) {
            const int s = ssrc[t];
            float ax = 0.f, ay = 0.f, az = 0.f;
            int j = t;
            while (j >= 0 && ssrc[j] == s) {
                ax += sPart[0][j]; ay += sPart[1][j]; az += sPart[2][j];
                --j;
            }
            atom_add_f32(&xout[3 * s + 0], ax);
            atom_add_f32(&xout[3 * s + 1], ay);
            atom_add_f32(&xout[3 * s + 2], az);
        }
    }
}

// ---------------- node ----------------
__global__ __launch_bounds__(256, 4) void node_kernel(
    const float* __restrict__ h, const ushort_t* __restrict__ hb,
    const ushort_t* __restrict__ maggr,
    const ushort_t* __restrict__ n1b, const float* __restrict__ nb1,
    const ushort_t* __restrict__ n2b, const float* __restrict__ nb2,
    const ushort_t* __restrict__ n3b, const float* __restrict__ nb3,
    float* __restrict__ hout) {
    __shared__ ushort_t sE[16384];
    const int t = threadIdx.x;
    const int lane = t & 63;
    const int wid = t >> 6;
    const int r15 = lane & 15;
    const int khi = lane >> 4;
    const int rhi = khi * 4;
    const int fb = wid * 32;
    const int n0 = blockIdx.x * 64;

    // stage [hb[n] | maggr[n]] (raw bf16, 16B chunks)
    const uint4* hb4 = (const uint4*)hb;
    const uint4* mg4 = (const uint4*)maggr;
#pragma unroll
    for (int it = 0; it < 8; ++it) {
        const int idx = it * 256 + t;
        const int e = idx >> 5, c = idx & 31;
        const int n = n0 + e;
        uint4 v = make_uint4(0u, 0u, 0u, 0u);
        if (n < N_NODES) v = (c < 16) ? hb4[(size_t)n * 16 + c] : mg4[(size_t)n * 16 + (c - 16)];
        const int ui = (e * 256 + c * 8) ^ ((e & 7) << 3);
        *(uint4*)(sE + ui) = v;
    }
    __syncthreads();

    // N1: K=256, wave owns 32 feats (2 row-blocks)
    f32x4 acc[2][4];
#pragma unroll
    for (int mi = 0; mi < 2; ++mi)
#pragma unroll
        for (int ni = 0; ni < 4; ++ni) acc[mi][ni] = (f32x4){0.f, 0.f, 0.f, 0.f};
#pragma unroll
    for (int ks = 0; ks < 8; ++ks) {
        const bf16x8 a0 = *(const bf16x8*)(n1b + (fb + r15) * 256 + ks * 32 + khi * 8);
        const bf16x8 a1 = *(const bf16x8*)(n1b + (fb + 16 + r15) * 256 + ks * 32 + khi * 8);
        bf16x8 b[4];
#pragma unroll
        for (int ni = 0; ni < 4; ++ni) {
            const int edge = ni * 16 + r15;
            const int ui = (edge * 256 + ks * 32 + khi * 8) ^ ((edge & 7) << 3);
            b[ni] = *(const bf16x8*)(sE + ui);
        }
#pragma unroll
        for (int ni = 0; ni < 4; ++ni) {
            acc[0][ni] = __builtin_amdgcn_mfma_f32_16x16x32_bf16(a0, b[ni], acc[0][ni], 0, 0, 0);
            acc[1][ni] = __builtin_amdgcn_mfma_f32_16x16x32_bf16(a1, b[ni], acc[1][ni], 0, 0, 0);
        }
    }
    __syncthreads();
    {
        const float4 bb0 = *(const float4*)&nb1[fb + rhi];
        const float4 bb1 = *(const float4*)&nb1[fb + 16 + rhi];
#pragma unroll
        for (int mi = 0; mi < 2; ++mi) {
            const float4 bb = mi ? bb1 : bb0;
#pragma unroll
            for (int ni = 0; ni < 4; ++ni) {
                const int edge = ni * 16 + r15;
                const float v0 = silu_f(acc[mi][ni][0] + bb.x);
                const float v1 = silu_f(acc[mi][ni][1] + bb.y);
                const float v2 = silu_f(acc[mi][ni][2] + bb.z);
                const float v3 = silu_f(acc[mi][ni][3] + bb.w);
                const int ui = (edge * 128 + fb + mi * 16 + rhi) ^ ((edge & 7) << 3);
                *(uint2*)(sE + ui) = make_uint2(pack2(v0, v1), pack2(v2, v3));
            }
        }
    }
    __syncthreads();

    // N2: two 16-feat halves; b[4] loaded before MFMAs
    {
#pragma unroll
        for (int half = 0; half < 2; ++half) {
            f32x4 a2[4];
#pragma unroll
            for (int ni = 0; ni < 4; ++ni) a2[ni] = (f32x4){0.f, 0.f, 0.f, 0.f};
            const int fbh = fb + half * 16;
#pragma unroll
            for (int ks = 0; ks < 4; ++ks) {
                const bf16x8 a0 = *(const bf16x8*)(n2b + (fbh + r15) * 128 + ks * 32 + khi * 8);
                bf16x8 b[4];
#pragma unroll
                for (int ni = 0; ni < 4; ++ni) {
                    const int edge = ni * 16 + r15;
                    const int ui = (edge * 128 + ks * 32 + khi * 8) ^ ((edge & 7) << 3);
                    b[ni] = *(const bf16x8*)(sE + ui);
                }
#pragma unroll
                for (int ni = 0; ni < 4; ++ni)
                    a2[ni] = __builtin_amdgcn_mfma_f32_16x16x32_bf16(a0, b[ni], a2[ni], 0, 0, 0);
            }
            const float4 bb = *(const float4*)&nb2[fbh + rhi];
#pragma unroll
            for (int ni = 0; ni < 4; ++ni) {
                const int edge = ni * 16 + r15;
                const float v0 = silu_f(a2[ni][0] + bb.x);
                const float v1 = silu_f(a2[ni][1] + bb.y);
                const float v2 = silu_f(a2[ni][2] + bb.z);
                const float v3 = silu_f(a2[ni][3] + bb.w);
                const int ui = (8192 + edge * 128 + fbh + rhi) ^ ((edge & 7) << 3);
                *(uint2*)(sE + ui) = make_uint2(pack2(v0, v1), pack2(v2, v3));
            }
        }
    }
    __syncthreads();

    // N3 + residual epilogue straight to global (f32, float4 stores)
    {
        f32x4 a3[2][4];
#pragma unroll
        for (int mi = 0; mi < 2; ++mi)
#pragma unroll
            for (int ni = 0; ni < 4; ++ni) a3[mi][ni] = (f32x4){0.f, 0.f, 0.f, 0.f};
#pragma unroll
        for (int ks = 0; ks < 4; ++ks) {
            const bf16x8 a0 = *(const bf16x8*)(n3b + (fb + r15) * 128 + ks * 32 + khi * 8);
            const bf16x8 a1 = *(const bf16x8*)(n3b + (fb + 16 + r15) * 128 + ks * 32 + khi * 8);
            bf16x8 b[4];
#pragma unroll
            for (int ni = 0; ni < 4; ++ni) {
                const int edge = ni * 16 + r15;
                const int ui = (8192 + edge * 128 + ks * 32 + khi * 8) ^ ((edge & 7) << 3);
                b[ni] = *(const bf16x8*)(sE + ui);
            }
#pragma unroll
            for (int ni = 0; ni < 4; ++ni) {
                a3[0][ni] = __builtin_amdgcn_mfma_f32_16x16x32_bf16(a0, b[ni], a3[0][ni], 0, 0, 0);
                a3[1][ni] = __builtin_amdgcn_mfma_f32_16x16x32_bf16(a1, b[ni], a3[1][ni], 0, 0, 0);
            }
        }
        const float4 bb0 = *(const float4*)&nb3[fb + rhi];
        const float4 bb1 = *(const float4*)&nb3[fb + 16 + rhi];
#pragma unroll
        for (int mi = 0; mi < 2; ++mi) {
            const float4 bb = mi ? bb1 : bb0;
#pragma unroll
            for (int ni = 0; ni < 4; ++ni) {
                const int n = n0 + ni * 16 + r15;
                if (n < N_NODES) {
                    const size_t o = (size_t)n * 128 + fb + mi * 16 + rhi;
                    const float4 hv = *(const float4*)&h[o];
                    float4 ov;
                    ov.x = hv.x + a3[mi][ni][0] + bb.x;
                    ov.y = hv.y + a3[mi][ni][1] + bb.y;
                    ov.z = hv.z + a3[mi][ni][2] + bb.z;
                    ov.w = hv.w + a3[mi][ni][3] + bb.w;
                    *(float4*)&hout[o] = ov;
                }
            }
        }
    }
}

extern "C" void kernel_launch(void* const* d_in, const int* in_sizes, int n_in,
                              void* d_out, int out_size, void* d_ws, size_t ws_size,
                              hipStream_t stream) {
    const float* x   = (const float*)d_in[0];
    const float* h   = (const float*)d_in[1];
    const int*   ei  = (const int*)d_in[2];
    const float* ew1 = (const float*)d_in[3];
    const float* eb1 = (const float*)d_in[4];
    const float* ew2 = (const float*)d_in[5];
    const float* eb2 = (const float*)d_in[6];
    const float* ew3 = (const float*)d_in[7];
    const float* eb3 = (const float*)d_in[8];
    const float* cw1 = (const float*)d_in[9];
    const float* cb1 = (const float*)d_in[10];
    const float* cw2 = (const float*)d_in[11];
    const float* cb2 = (const float*)d_in[12];
    const float* nw1 = (const float*)d_in[13];
    const float* nb1 = (const float*)d_in[14];
    const float* nw2 = (const float*)d_in[15];
    const float* nb2 = (const float*)d_in[16];
    const float* nw3 = (const float*)d_in[17];
    const float* nb3 = (const float*)d_in[18];

    float* out  = (float*)d_out;
    float* xout = out;                       // [50000,3]
    float* hout = out + (size_t)N_NODES * 3; // [50000,128]
    ushort_t* wsu = (ushort_t*)d_ws;

    ushort_t* maggr = wsu + U_MAGGR;
    const ushort_t* hb  = wsu + U_HB;
    const ushort_t* wab = wsu + U_W1B;       // Wab 256x128
    const ushort_t* w2b = wsu + U_W2B;
    const ushort_t* w3b = wsu + U_W3B;
    const ushort_t* c1b = wsu + U_C1B;
    const ushort_t* n1b = wsu + U_N1B;
    const ushort_t* n2b = wsu + U_N2B;
    const ushort_t* n3b = wsu + U_N3B;
    const float* w1d2 = (const float*)(wsu + U_W1D2);
    ushort_t* wcb = wsu + U_WC;
    float* bcv = (float*)(wsu + U_BC);
    int2* sd = (int2*)(wsu + U_SD);
    unsigned int* cnt = (unsigned int*)(wsu + U_CNT);
    unsigned int* ptr = (unsigned int*)(wsu + U_PTR);
    unsigned int* rank = (unsigned int*)(wsu + U_RANK);

    // AB table (bf16 [N][256] = 25.6 MB) stashed in the hout region of d_out;
    // node_kernel fully overwrites hout afterwards.
    ushort_t* abp = (ushort_t*)hout;

    hipMemsetAsync(cnt, 0, 50048 * sizeof(unsigned int), stream);

    const long prep_total = 800000L + 800000L + 32768 + 3 * 16384 + 32768 + 2 * 16384 + 128 + 37500 + N_EDGES;
    const int prep_blocks = (int)((prep_total + 255) / 256);
    prep_kernel<<<prep_blocks, 256, 0, stream>>>(x, h, ew1, ew2, ew3, cw1, nw1, nw2, nw3,
                                                 ei, wsu, xout);

    const int nAB = (N_NODES + 63) / 64;     // 782; +1 = Wc block, +2 = scan block
    ab_kernel<<<nAB + 2, 256, 0, stream>>>(hb, wab, eb1, abp,
                                           c1b, ew3, eb3, cb1, wcb, bcv,
                                           cnt, ptr, nAB);

    scatter_kernel<<<(N_EDGES + 255) / 256, 256, 0, stream>>>(ei, ptr, rank, sd);

    edge_kernel<<<N_EDGES / EDG, 512, 0, stream>>>(x, abp, sd,
                                                   w1d2, w2b, eb2, w3b, eb3,
                                                   wcb, bcv, cw2, cb2,
                                                   xout, maggr);

    node_kernel<<<(N_NODES + 63) / 64, 256, 0, stream>>>(h, hb, maggr,
                                                         n1b, nb1, n2b, nb2, n3b, nb3,
                                                         hout);
}

// Round 8
// 289.780 us; speedup vs baseline: 1.3819x; 1.0078x over previous
//
#include <hip/hip_runtime.h>
#include <hip/hip_bf16.h>

#define N_NODES 50000
#define N_EDGES 640000
#define HID 128
#define EDG 80           // edges per edge-block (80 -> 45KB LDS -> 3 blocks/CU)
#define ACT2 (EDG * 128) // ushort offset of act2 buffer in sE

typedef unsigned short ushort_t;
typedef __attribute__((ext_vector_type(8))) short bf16x8;   // 8 bf16 = 4 VGPR (MFMA A/B frag)
typedef __attribute__((ext_vector_type(4))) float f32x4;    // MFMA C/D frag

// ws layout (ushort units from base):
//   maggr  [0,        6400000)   bf16 N x 128 (pk-atomic accumulated)
//   hb     [6400000, 12800000)   bf16 N x 128 (h pre-converted)
//   w1b    [12800000,12832768)   Wab 256 x 128: rows 0..127 = ew1[:,0:128] (A), rows 128..255 = ew1[:,128:256] (B)
//   w2b    [12832768,12849152)   128 x 128
//   w3b    [12849152,12865536)   128 x 128
//   c1b    [12865536,12881920)   128 x 128 (bf16 cw1; consumed by wc block)
//   n1b    [12881920,12914688)   128 x 256
//   n2b    [12914688,12931072)   128 x 128
//   n3b    [12931072,12947456)   128 x 128
//   w1d2   (float*) at ushort 12947456, 128 f32 = ew1[:,256]
//   wcb    [12947712,12964096)   128 x 128 bf16 = Wc1 @ W3 (composed coord weight)
//   bc     (float*) at ushort 12964096, 128 f32 = Wc1 @ eb3 + cb1
//   sd     [12964352,15524352)   int2[640000] src-sorted (src,dst) pairs
//   cnt    [15524352,15624448)   u32[50048]  per-src degree histogram
//   ptr    [15624448,15724544)   u32[50048]  exclusive scan of cnt
//   rank   [15724544,17004544)   u32[640000] per-edge rank within its src group
// AB table (bf16 N x 256 = 25.6 MB) lives in d_out's hout region (dead until node_kernel
// fully overwrites it): A[n] = h@W1a^T in feats 0..127, B[n] = h@W1b^T + eb1 in feats 128..255.
#define U_MAGGR 0
#define U_HB    6400000
#define U_W1B   12800000
#define U_W2B   12832768
#define U_W3B   12849152
#define U_C1B   12865536
#define U_N1B   12881920
#define U_N2B   12914688
#define U_N3B   12931072
#define U_W1D2  12947456
#define U_WC    12947712
#define U_BC    12964096
#define U_SD    12964352
#define U_CNT   15524352
#define U_PTR   15624448
#define U_RANK  15724544

// silu via exp2 + fast rcp (bf16-output tolerance; saves div fixup sequence)
__device__ __forceinline__ float silu_f(float v) {
    const float e = __builtin_amdgcn_exp2f(v * -1.442695041f);
    return v * __builtin_amdgcn_rcpf(1.0f + e);
}

__device__ __forceinline__ ushort_t f2b(float f) {
    __hip_bfloat16 b = __float2bfloat16(f);          // RNE
    return __builtin_bit_cast(ushort_t, b);
}
__device__ __forceinline__ float b2f(ushort_t u) {
    union { float f; unsigned int i; } v; v.i = ((unsigned int)u) << 16; return v.f;
}
__device__ __forceinline__ float u2f(unsigned int u) {
    union { float f; unsigned int i; } v; v.i = u; return v.f;
}
__device__ __forceinline__ unsigned int pack2(float a, float b) {
    return (unsigned int)f2b(a) | ((unsigned int)f2b(b) << 16);
}
// uint4 of 8 bf16 -> 8 f32 (1 VALU op each: shl or and)
__device__ __forceinline__ void up8(const uint4& u, float* f) {
    f[0] = u2f(u.x << 16); f[1] = u2f(u.x & 0xffff0000u);
    f[2] = u2f(u.y << 16); f[3] = u2f(u.y & 0xffff0000u);
    f[4] = u2f(u.z << 16); f[5] = u2f(u.z & 0xffff0000u);
    f[6] = u2f(u.w << 16); f[7] = u2f(u.w & 0xffff0000u);
}
__device__ __forceinline__ void atom_add_f32(float* p, float v) { unsafeAtomicAdd(p, v); }

// packed bf16x2 atomic add (gfx950: global_atomic_pk_add_bf16)
__device__ __forceinline__ void atom_pk_bf16(ushort_t* p, unsigned int v) {
#if __has_builtin(__builtin_amdgcn_global_atomic_fadd_v2bf16)
    typedef __attribute__((ext_vector_type(2))) short s2;
    s2 sv = __builtin_bit_cast(s2, v);
    __builtin_amdgcn_global_atomic_fadd_v2bf16((__attribute__((address_space(1))) s2*)p, sv);
#else
    unsigned int* up = (unsigned int*)p;
    unsigned int old = __hip_atomic_load(up, __ATOMIC_RELAXED, __HIP_MEMORY_SCOPE_AGENT), assumed;
    do {
        assumed = old;
        float lo = b2f((ushort_t)(assumed & 0xffff)) + b2f((ushort_t)(v & 0xffff));
        float hi = b2f((ushort_t)(assumed >> 16)) + b2f((ushort_t)(v >> 16));
        unsigned int nv = (unsigned int)f2b(lo) | ((unsigned int)f2b(hi) << 16);
        old = atomicCAS(up, assumed, nv);
    } while (old != assumed);
#endif
}

// ---------------- prep (vectorized; hist also records per-edge rank; cnt pre-zeroed) ----------------
__global__ void prep_kernel(const float* __restrict__ x, const float* __restrict__ h,
                            const float* __restrict__ ew1, const float* __restrict__ ew2,
                            const float* __restrict__ ew3, const float* __restrict__ cw1,
                            const float* __restrict__ nw1, const float* __restrict__ nw2,
                            const float* __restrict__ nw3, const int* __restrict__ ei,
                            ushort_t* __restrict__ wsu, float* __restrict__ xout) {
    long i = (long)blockIdx.x * 256 + threadIdx.x;
    if (i < 800000) {   // maggr zero, 16B stores
        ((uint4*)(wsu + U_MAGGR))[i] = make_uint4(0u, 0u, 0u, 0u);
        return;
    }
    i -= 800000;
    if (i < 800000) {   // h -> bf16, 8 floats per thread
        const float4* h4 = (const float4*)h;
        const float4 f0 = h4[2 * i], f1 = h4[2 * i + 1];
        ((uint4*)(wsu + U_HB))[i] = make_uint4(pack2(f0.x, f0.y), pack2(f0.z, f0.w),
                                               pack2(f1.x, f1.y), pack2(f1.z, f1.w));
        return;
    }
    i -= 800000;
    if (i < 32768) {
        // Wab[f][k]: f<128 -> ew1[f][k] (A half), f>=128 -> ew1[f-128][128+k] (B half)
        const int f = (int)(i >> 7);
        const int k = (int)(i & 127);
        const int src = (f < 128) ? (f * 257 + k) : ((f - 128) * 257 + 128 + k);
        wsu[U_W1B + i] = f2b(ew1[src]);
        return;
    }
    i -= 32768;
    if (i < 16384) { wsu[U_W2B + i] = f2b(ew2[i]); return; }
    i -= 16384;
    if (i < 16384) { wsu[U_W3B + i] = f2b(ew3[i]); return; }
    i -= 16384;
    if (i < 16384) { wsu[U_C1B + i] = f2b(cw1[i]); return; }
    i -= 16384;
    if (i < 32768) { wsu[U_N1B + i] = f2b(nw1[i]); return; }
    i -= 32768;
    if (i < 16384) { wsu[U_N2B + i] = f2b(nw2[i]); return; }
    i -= 16384;
    if (i < 16384) { wsu[U_N3B + i] = f2b(nw3[i]); return; }
    i -= 16384;
    if (i < 128) { ((float*)(wsu + U_W1D2))[i] = ew1[i * 257 + 256]; return; }
    i -= 128;
    if (i < 37500) { ((float4*)xout)[i] = ((const float4*)x)[i]; return; }
    i -= 37500;
    if (i < N_EDGES) {
        const unsigned int r = atomicAdd(((unsigned int*)(wsu + U_CNT)) + ei[i], 1u);
        ((unsigned int*)(wsu + U_RANK))[i] = r;
    }
}

// ---------------- counting-sort scatter, atomic-free: pos = ptr[s] + rank[e] ----------------
__global__ void scatter_kernel(const int* __restrict__ ei, const unsigned int* __restrict__ ptr,
                               const unsigned int* __restrict__ rank, int2* __restrict__ sd) {
    const int e = blockIdx.x * 256 + threadIdx.x;
    if (e >= N_EDGES) return;
    const int s = ei[e], d = ei[N_EDGES + e];
    const unsigned int pos = ptr[s] + rank[e];
    sd[pos] = make_int2(s, d);
}

// ---------------- AB precompute + Wc compose + scan (extra blocks) ----------------
// Blocks 0..nAB-1: AB[n] = [h@W1a^T | h@W1b^T + eb1]   (64 nodes/block, 4 waves)
// Block nAB:       Wc = Wc1 @ W3 (bf16) and bc = Wc1 @ eb3 + cb1
// Block nAB+1:     exclusive scan cnt -> ptr (parallel, hidden under AB blocks)
__global__ __launch_bounds__(256, 4) void ab_kernel(
    const ushort_t* __restrict__ hb, const ushort_t* __restrict__ wab,
    const float* __restrict__ eb1, ushort_t* __restrict__ abp,
    const ushort_t* __restrict__ c1b, const float* __restrict__ ew3,
    const float* __restrict__ eb3, const float* __restrict__ cb1,
    ushort_t* __restrict__ wcb, float* __restrict__ bcv,
    const unsigned int* __restrict__ cnt, unsigned int* __restrict__ ptr, int nAB) {
    __shared__ ushort_t sH[16384];   // AB path uses first 8192; Wc block uses all 32 KB
    const int t = threadIdx.x;
    const int lane = t & 63;
    const int wid = t >> 6;          // 0..3
    const int r15 = lane & 15;
    const int khi = lane >> 4;
    const int rhi = khi * 4;

    if ((int)blockIdx.x == nAB + 1) {
        // ---- parallel exclusive scan of cnt[50000] -> ptr ----
        __shared__ unsigned int sSum[256];
        const int lo = t * 196;
        const int hi = (lo + 196 < N_NODES) ? lo + 196 : N_NODES;
        unsigned int s = 0;
#pragma unroll 4
        for (int i = lo; i < hi; ++i) s += cnt[i];
        sSum[t] = s;
        __syncthreads();
#pragma unroll
        for (int off = 1; off < 256; off <<= 1) {
            const unsigned int v = (t >= off) ? sSum[t - off] : 0u;
            __syncthreads();
            sSum[t] += v;
            __syncthreads();
        }
        unsigned int run = (t == 0) ? 0u : sSum[t - 1];
#pragma unroll 4
        for (int i = lo; i < hi; ++i) { const unsigned int c = cnt[i]; ptr[i] = run; run += c; }
        return;
    }

    if ((int)blockIdx.x == nAB) {
        // ---- stage Bt[k][m] = ew3[m][k] bf16, XOR-swizzled ----
        for (int i = t; i < 16384; i += 256) {
            const int m = i >> 7, k = i & 127;
            sH[(k * 128 + m) ^ ((k & 7) << 3)] = f2b(ew3[i]);
        }
        __syncthreads();
        // ---- Wc[f][k] = sum_m Wc1[f][m] * W3[m][k] ----
#pragma unroll
        for (int kh = 0; kh < 2; ++kh) {
#pragma unroll
            for (int fi = 0; fi < 2; ++fi) {
                const int f0 = wid * 32 + fi * 16;
                const int kc = kh * 64;
                f32x4 acc[4];
#pragma unroll
                for (int ni = 0; ni < 4; ++ni) acc[ni] = (f32x4){0.f, 0.f, 0.f, 0.f};
#pragma unroll
                for (int ks = 0; ks < 4; ++ks) {
                    const bf16x8 a0 = *(const bf16x8*)(c1b + (f0 + r15) * 128 + ks * 32 + khi * 8);
                    bf16x8 b[4];
#pragma unroll
                    for (int ni = 0; ni < 4; ++ni) {
                        const int kk = kc + ni * 16 + r15;
                        b[ni] = *(const bf16x8*)(sH + ((kk * 128 + ks * 32 + khi * 8) ^ ((kk & 7) << 3)));
                    }
#pragma unroll
                    for (int ni = 0; ni < 4; ++ni)
                        acc[ni] = __builtin_amdgcn_mfma_f32_16x16x32_bf16(a0, b[ni], acc[ni], 0, 0, 0);
                }
#pragma unroll
                for (int ni = 0; ni < 4; ++ni) {
                    const int kk = kc + ni * 16 + r15;
#pragma unroll
                    for (int j = 0; j < 4; ++j)
                        wcb[(f0 + rhi + j) * 128 + kk] = f2b(acc[ni][j]);
                }
            }
        }
        // ---- bc[f] = cb1[f] + sum_m Wc1[f][m] * eb3[m] ----
        {
            const int f = t >> 1, hf = t & 1;
            float s = 0.f;
            const int m0 = hf * 64;
#pragma unroll 8
            for (int m = m0; m < m0 + 64; ++m)
                s = fmaf(b2f(c1b[f * 128 + m]), eb3[m], s);
            s += __shfl_xor(s, 1);
            if (hf == 0) bcv[f] = cb1[f] + s;
        }
        return;
    }

    const int fb = wid * 64;         // 64 feats per wave (4 row-blocks)
    const int n0 = blockIdx.x * 64;

    const uint4* hb4 = (const uint4*)hb;
#pragma unroll
    for (int it = 0; it < 4; ++it) {
        const int idx = it * 256 + t;          // 1024 tasks: 64 nodes x 16 chunks
        const int e = idx >> 4, c = idx & 15;
        const int n = n0 + e;
        uint4 v = make_uint4(0u, 0u, 0u, 0u);
        if (n < N_NODES) v = hb4[(size_t)n * 16 + c];
        const int ui = (e * 128 + c * 8) ^ ((e & 7) << 3);
        *(uint4*)(sH + ui) = v;
    }
    __syncthreads();

    f32x4 acc[4][4];
#pragma unroll
    for (int mi = 0; mi < 4; ++mi)
#pragma unroll
        for (int ni = 0; ni < 4; ++ni) acc[mi][ni] = (f32x4){0.f, 0.f, 0.f, 0.f};
#pragma unroll
    for (int ks = 0; ks < 4; ++ks) {
        bf16x8 a[4];
#pragma unroll
        for (int mi = 0; mi < 4; ++mi)
            a[mi] = *(const bf16x8*)(wab + (fb + mi * 16 + r15) * 128 + ks * 32 + khi * 8);
        bf16x8 b[4];
#pragma unroll
        for (int ni = 0; ni < 4; ++ni) {
            const int e = ni * 16 + r15;
            const int ui = (e * 128 + ks * 32 + khi * 8) ^ ((e & 7) << 3);
            b[ni] = *(const bf16x8*)(sH + ui);
        }
#pragma unroll
        for (int mi = 0; mi < 4; ++mi)
#pragma unroll
            for (int ni = 0; ni < 4; ++ni)
                acc[mi][ni] = __builtin_amdgcn_mfma_f32_16x16x32_bf16(a[mi], b[ni], acc[mi][ni], 0, 0, 0);
    }

#pragma unroll
    for (int mi = 0; mi < 4; ++mi) {
        const int f0 = fb + mi * 16 + rhi;     // entire 16-block is on one side of 128
        float4 bb = make_float4(0.f, 0.f, 0.f, 0.f);
        if (f0 >= 128) bb = *(const float4*)&eb1[f0 - 128];
#pragma unroll
        for (int ni = 0; ni < 4; ++ni) {
            const int n = n0 + ni * 16 + r15;
            if (n < N_NODES) {
                *(uint2*)(abp + (size_t)n * 256 + f0) =
                    make_uint2(pack2(acc[mi][ni][0] + bb.x, acc[mi][ni][1] + bb.y),
                               pack2(acc[mi][ni][2] + bb.z, acc[mi][ni][3] + bb.w));
            }
        }
    }
}

// swapped dense layer, K=128: D[feat][edge] = W(128x128) x act^T.
// 8 waves: wave wid owns 16 output feats x NE*16 edges.
// src rows: [NE*16 edges][128 ushorts], XOR-swizzled ^((edge&7)<<3) (ushort units).
template <bool ACT, int NE>
__device__ __forceinline__ void dense128(ushort_t* sE, int srcBase, int dstBase,
                                         const ushort_t* __restrict__ W,
                                         const float* __restrict__ bias,
                                         int r15, int khi, int rhi, int fb) {
    f32x4 acc[NE];
#pragma unroll
    for (int ni = 0; ni < NE; ++ni) acc[ni] = (f32x4){0.f, 0.f, 0.f, 0.f};
#pragma unroll
    for (int ks = 0; ks < 4; ++ks) {
        const bf16x8 a0 = *(const bf16x8*)(W + (fb + r15) * 128 + ks * 32 + khi * 8);
        bf16x8 b[NE];
#pragma unroll
        for (int ni = 0; ni < NE; ++ni) {
            const int edge = ni * 16 + r15;
            const int ui = (srcBase + edge * 128 + ks * 32 + khi * 8) ^ ((edge & 7) << 3);
            b[ni] = *(const bf16x8*)(sE + ui);
        }
#pragma unroll
        for (int ni = 0; ni < NE; ++ni)
            acc[ni] = __builtin_amdgcn_mfma_f32_16x16x32_bf16(a0, b[ni], acc[ni], 0, 0, 0);
    }
    const float4 bb = *(const float4*)&bias[fb + rhi];
#pragma unroll
    for (int ni = 0; ni < NE; ++ni) {
        const int edge = ni * 16 + r15;
        float v0 = acc[ni][0] + bb.x;
        float v1 = acc[ni][1] + bb.y;
        float v2 = acc[ni][2] + bb.z;
        float v3 = acc[ni][3] + bb.w;
        if (ACT) { v0 = silu_f(v0); v1 = silu_f(v1); v2 = silu_f(v2); v3 = silu_f(v3); }
        const int ui = (dstBase + edge * 128 + fb + rhi) ^ ((edge & 7) << 3);
        *(uint2*)(sE + ui) = make_uint2(pack2(v0, v1), pack2(v2, v3));
    }
}

// ---------------- edge ----------------
// 512 threads / 8 waves per block, 80 src-sorted edges per block (3 blocks/CU, 24 waves).
// Phases: P0 gather-issue+meta | P1 act1 stage | P2 w2 | P3 w3->LDS + c1'(composed)->dot
//         P4 segmented aggr (f32 partials -> ~1 atomic per segment) + segmented xout
__global__ __launch_bounds__(512, 6) void edge_kernel(
    const float* __restrict__ x, const ushort_t* __restrict__ ab,
    const int2* __restrict__ sd,
    const float* __restrict__ w1d2,
    const ushort_t* __restrict__ w2b, const float* __restrict__ eb2,
    const ushort_t* __restrict__ w3b, const float* __restrict__ eb3,
    const ushort_t* __restrict__ wcb, const float* __restrict__ bcv,
    const float* __restrict__ cw2, const float* __restrict__ cb2,
    float* __restrict__ xout, ushort_t* __restrict__ maggr) {
    __shared__ ushort_t sE[2 * ACT2];  // 40 KB: act1/m_ij @0, act2 @ACT2 ([80][128] each)
    __shared__ float srel[EDG][3];
    __shared__ float sd2[EDG];
    __shared__ int ssrc[EDG];
    __shared__ float sPart[8][EDG];  // wave partials; rows 0..2 reused as xout contributions

    const int t = threadIdx.x;
    const int lane = t & 63;
    const int wid = t >> 6;          // 0..7
    const int r15 = lane & 15;
    const int khi = lane >> 4;       // 0..3
    const int rhi = khi * 4;
    const int fb = wid * 16;         // 16 feats per wave
    const int e0 = blockIdx.x * EDG;

    // ---- P0: issue AB gathers; c = t&15 is iteration-invariant, e = it*32 + (t>>4).
    //          1280 tasks = 80 edges x 16 chunks; 3 iters with tail guard.
    //          t<EDG concurrently builds srel/sd2/ssrc.
    uint4 va[3], vb[3];
    const int c = t & 15;
    const int ebase = t >> 4;        // 0..31
    {
        const uint4* ab4 = (const uint4*)ab;
#pragma unroll
        for (int it = 0; it < 3; ++it) {
            const int e = it * 32 + ebase;
            if (e < EDG) {
                const int2 p = sd[e0 + e];
                va[it] = ab4[(size_t)p.x * 32 + c];         // A half of AB[src]
                vb[it] = ab4[(size_t)p.y * 32 + 16 + c];    // B half of AB[dst]
            }
        }
    }
    if (t < EDG) {
        const int2 p = sd[e0 + t];
        ssrc[t] = p.x;
        const float rx = x[3 * p.x] - x[3 * p.y];
        const float ry = x[3 * p.x + 1] - x[3 * p.y + 1];
        const float rz = x[3 * p.x + 2] - x[3 * p.y + 2];
        srel[t][0] = rx; srel[t][1] = ry; srel[t][2] = rz;
        sd2[t] = rx * rx + ry * ry + rz * rz;
    }
    __syncthreads();

    // ---- P1: act1 = silu(A[src] + B[dst] + d2*w1d2); w1d2 loads hoisted (c fixed) ----
    {
        const float4 w0 = *(const float4*)&w1d2[c * 8];
        const float4 w1 = *(const float4*)&w1d2[c * 8 + 4];
#pragma unroll
        for (int it = 0; it < 3; ++it) {
            const int e = it * 32 + ebase;
            if (e < EDG) {
                const float d2 = sd2[e];
                float fa[8], fbv[8];
                up8(va[it], fa);
                up8(vb[it], fbv);
                const float v0 = silu_f(fmaf(d2, w0.x, fa[0] + fbv[0]));
                const float v1 = silu_f(fmaf(d2, w0.y, fa[1] + fbv[1]));
                const float v2 = silu_f(fmaf(d2, w0.z, fa[2] + fbv[2]));
                const float v3 = silu_f(fmaf(d2, w0.w, fa[3] + fbv[3]));
                const float v4 = silu_f(fmaf(d2, w1.x, fa[4] + fbv[4]));
                const float v5 = silu_f(fmaf(d2, w1.y, fa[5] + fbv[5]));
                const float v6 = silu_f(fmaf(d2, w1.z, fa[6] + fbv[6]));
                const float v7 = silu_f(fmaf(d2, w1.w, fa[7] + fbv[7]));
                uint4 st;
                st.x = pack2(v0, v1); st.y = pack2(v2, v3);
                st.z = pack2(v4, v5); st.w = pack2(v6, v7);
                *(uint4*)(sE + ((e * 128 + c * 8) ^ ((e & 7) << 3))) = st;
            }
        }
    }
    __syncthreads();

    // ---- P2: w2 dense: act1 -> silu -> act2 @ACT2 ----
    dense128<true, EDG / 16>(sE, 0, ACT2, w2b, eb2, r15, khi, rhi, fb);
    __syncthreads();

    // ---- P3a: w3 dense: act2 -> m_ij @0 (packed LDS store) ----
    dense128<false, EDG / 16>(sE, ACT2, 0, w3b, eb3, r15, khi, rhi, fb);

    // ---- P3b: c1' dense with composed Wc (reads act2 directly) -> silu -> dot(cw2) ----
    {
        f32x4 acc[EDG / 16];
#pragma unroll
        for (int ni = 0; ni < EDG / 16; ++ni) acc[ni] = (f32x4){0.f, 0.f, 0.f, 0.f};
#pragma unroll
        for (int ks = 0; ks < 4; ++ks) {
            const bf16x8 a0 = *(const bf16x8*)(wcb + (fb + r15) * 128 + ks * 32 + khi * 8);
            bf16x8 b[EDG / 16];
#pragma unroll
            for (int ni = 0; ni < EDG / 16; ++ni) {
                const int edge = ni * 16 + r15;
                const int u = (ACT2 + edge * 128 + ks * 32 + khi * 8) ^ ((edge & 7) << 3);
                b[ni] = *(const bf16x8*)(sE + u);
            }
#pragma unroll
            for (int ni = 0; ni < EDG / 16; ++ni)
                acc[ni] = __builtin_amdgcn_mfma_f32_16x16x32_bf16(a0, b[ni], acc[ni], 0, 0, 0);
        }
        const float4 bb = *(const float4*)&bcv[fb + rhi];
        const float4 cw = *(const float4*)&cw2[fb + rhi];
        float p[EDG / 16];
#pragma unroll
        for (int ni = 0; ni < EDG / 16; ++ni) {
            float s = silu_f(acc[ni][0] + bb.x) * cw.x;
            s = fmaf(silu_f(acc[ni][1] + bb.y), cw.y, s);
            s = fmaf(silu_f(acc[ni][2] + bb.z), cw.z, s);
            s = fmaf(silu_f(acc[ni][3] + bb.w), cw.w, s);
            p[ni] = s;
        }
#pragma unroll
        for (int ni = 0; ni < EDG / 16; ++ni) {
            p[ni] += __shfl_xor(p[ni], 16);
            p[ni] += __shfl_xor(p[ni], 32);
        }
        if (khi == 0) {
#pragma unroll
            for (int ni = 0; ni < EDG / 16; ++ni) sPart[wid][ni * 16 + r15] = p[ni];
        }
    }
    __syncthreads();

    // coef + per-edge xout contributions into sPart rows 0..2 (column-private)
    if (t < EDG) {
        float s = sPart[0][t];
#pragma unroll
        for (int w = 1; w < 8; ++w) s += sPart[w][t];
        const float coef = tanhf(s + cb2[0]);
        sPart[0][t] = srel[t][0] * coef;
        sPart[1][t] = srel[t][1] * coef;
        sPart[2][t] = srel[t][2] * coef;
    }

    // ---- P4: segmented maggr aggregation. thread = (dw 0..63, strip 0..7), 10 edges/strip;
    //          f32 partials per src-segment, one pk-atomic per boundary. Wave-uniform branches.
    {
        const int dw = t & 63;
        const int rs = t >> 6;
        float lo = 0.f, hi = 0.f;
        int cur = ssrc[rs * 10];
#pragma unroll
        for (int j = 0; j < 10; ++j) {
            const int e = rs * 10 + j;
            const int s = ssrc[e];
            if (s != cur) {
                atom_pk_bf16(maggr + (size_t)cur * 128 + dw * 2, pack2(lo, hi));
                lo = 0.f; hi = 0.f; cur = s;
            }
            const unsigned int v = *(const unsigned int*)(sE + ((e * 128 + dw * 2) ^ ((e & 7) << 3)));
            lo += b2f((ushort_t)(v & 0xffff));
            hi += b2f((ushort_t)(v >> 16));
        }
        atom_pk_bf16(maggr + (size_t)cur * 128 + dw * 2, pack2(lo, hi));
    }
    __syncthreads();

    // ---- segmented xout: boundary-last lane sums its segment, 3 atomics per segment ----
    if (t < EDG) {
        const bool last = (t == EDG - 1) || (ssrc[t + 1] != ssrc[t]);
        if (last) {
            const int s = ssrc[t];
            float ax = 0.f, ay = 0.f, az = 0.f;
            int j = t;
            while (j >= 0 && ssrc[j] == s) {
                ax += sPart[0][j]; ay += sPart[1][j]; az += sPart[2][j];
                --j;
            }
            atom_add_f32(&xout[3 * s + 0], ax);
            atom_add_f32(&xout[3 * s + 1], ay);
            atom_add_f32(&xout[3 * s + 2], az);
        }
    }
}

// ---------------- node ----------------
__global__ __launch_bounds__(256, 4) void node_kernel(
    const float* __restrict__ h, const ushort_t* __restrict__ hb,
    const ushort_t* __restrict__ maggr,
    const ushort_t* __restrict__ n1b, const float* __restrict__ nb1,
    const ushort_t* __restrict__ n2b, const float* __restrict__ nb2,
    const ushort_t* __restrict__ n3b, const float* __restrict__ nb3,
    float* __restrict__ hout) {
    __shared__ ushort_t sE[16384];
    const int t = threadIdx.x;
    const int lane = t & 63;
    const int wid = t >> 6;
    const int r15 = lane & 15;
    const int khi = lane >> 4;
    const int rhi = khi * 4;
    const int fb = wid * 32;
    const int n0 = blockIdx.x * 64;

    // stage [hb[n] | maggr[n]] (raw bf16, 16B chunks)
    const uint4* hb4 = (const uint4*)hb;
    const uint4* mg4 = (const uint4*)maggr;
#pragma unroll
    for (int it = 0; it < 8; ++it) {
        const int idx = it * 256 + t;
        const int e = idx >> 5, c = idx & 31;
        const int n = n0 + e;
        uint4 v = make_uint4(0u, 0u, 0u, 0u);
        if (n < N_NODES) v = (c < 16) ? hb4[(size_t)n * 16 + c] : mg4[(size_t)n * 16 + (c - 16)];
        const int ui = (e * 256 + c * 8) ^ ((e & 7) << 3);
        *(uint4*)(sE + ui) = v;
    }
    __syncthreads();

    // N1: K=256, wave owns 32 feats (2 row-blocks)
    f32x4 acc[2][4];
#pragma unroll
    for (int mi = 0; mi < 2; ++mi)
#pragma unroll
        for (int ni = 0; ni < 4; ++ni) acc[mi][ni] = (f32x4){0.f, 0.f, 0.f, 0.f};
#pragma unroll
    for (int ks = 0; ks < 8; ++ks) {
        const bf16x8 a0 = *(const bf16x8*)(n1b + (fb + r15) * 256 + ks * 32 + khi * 8);
        const bf16x8 a1 = *(const bf16x8*)(n1b + (fb + 16 + r15) * 256 + ks * 32 + khi * 8);
        bf16x8 b[4];
#pragma unroll
        for (int ni = 0; ni < 4; ++ni) {
            const int edge = ni * 16 + r15;
            const int ui = (edge * 256 + ks * 32 + khi * 8) ^ ((edge & 7) << 3);
            b[ni] = *(const bf16x8*)(sE + ui);
        }
#pragma unroll
        for (int ni = 0; ni < 4; ++ni) {
            acc[0][ni] = __builtin_amdgcn_mfma_f32_16x16x32_bf16(a0, b[ni], acc[0][ni], 0, 0, 0);
            acc[1][ni] = __builtin_amdgcn_mfma_f32_16x16x32_bf16(a1, b[ni], acc[1][ni], 0, 0, 0);
        }
    }
    __syncthreads();
    {
        const float4 bb0 = *(const float4*)&nb1[fb + rhi];
        const float4 bb1 = *(const float4*)&nb1[fb + 16 + rhi];
#pragma unroll
        for (int mi = 0; mi < 2; ++mi) {
            const float4 bb = mi ? bb1 : bb0;
#pragma unroll
            for (int ni = 0; ni < 4; ++ni) {
                const int edge = ni * 16 + r15;
                const float v0 = silu_f(acc[mi][ni][0] + bb.x);
                const float v1 = silu_f(acc[mi][ni][1] + bb.y);
                const float v2 = silu_f(acc[mi][ni][2] + bb.z);
                const float v3 = silu_f(acc[mi][ni][3] + bb.w);
                const int ui = (edge * 128 + fb + mi * 16 + rhi) ^ ((edge & 7) << 3);
                *(uint2*)(sE + ui) = make_uint2(pack2(v0, v1), pack2(v2, v3));
            }
        }
    }
    __syncthreads();

    // N2: two 16-feat halves; b[4] loaded before MFMAs
    {
#pragma unroll
        for (int half = 0; half < 2; ++half) {
            f32x4 a2[4];
#pragma unroll
            for (int ni = 0; ni < 4; ++ni) a2[ni] = (f32x4){0.f, 0.f, 0.f, 0.f};
            const int fbh = fb + half * 16;
#pragma unroll
            for (int ks = 0; ks < 4; ++ks) {
                const bf16x8 a0 = *(const bf16x8*)(n2b + (fbh + r15) * 128 + ks * 32 + khi * 8);
                bf16x8 b[4];
#pragma unroll
                for (int ni = 0; ni < 4; ++ni) {
                    const int edge = ni * 16 + r15;
                    const int ui = (edge * 128 + ks * 32 + khi * 8) ^ ((edge & 7) << 3);
                    b[ni] = *(const bf16x8*)(sE + ui);
                }
#pragma unroll
                for (int ni = 0; ni < 4; ++ni)
                    a2[ni] = __builtin_amdgcn_mfma_f32_16x16x32_bf16(a0, b[ni], a2[ni], 0, 0, 0);
            }
            const float4 bb = *(const float4*)&nb2[fbh + rhi];
#pragma unroll
            for (int ni = 0; ni < 4; ++ni) {
                const int edge = ni * 16 + r15;
                const float v0 = silu_f(a2[ni][0] + bb.x);
                const float v1 = silu_f(a2[ni][1] + bb.y);
                const float v2 = silu_f(a2[ni][2] + bb.z);
                const float v3 = silu_f(a2[ni][3] + bb.w);
                const int ui = (8192 + edge * 128 + fbh + rhi) ^ ((edge & 7) << 3);
                *(uint2*)(sE + ui) = make_uint2(pack2(v0, v1), pack2(v2, v3));
            }
        }
    }
    __syncthreads();

    // N3 + residual epilogue straight to global (f32, float4 stores)
    {
        f32x4 a3[2][4];
#pragma unroll
        for (int mi = 0; mi < 2; ++mi)
#pragma unroll
            for (int ni = 0; ni < 4; ++ni) a3[mi][ni] = (f32x4){0.f, 0.f, 0.f, 0.f};
#pragma unroll
        for (int ks = 0; ks < 4; ++ks) {
            const bf16x8 a0 = *(const bf16x8*)(n3b + (fb + r15) * 128 + ks * 32 + khi * 8);
            const bf16x8 a1 = *(const bf16x8*)(n3b + (fb + 16 + r15) * 128 + ks * 32 + khi * 8);
            bf16x8 b[4];
#pragma unroll
            for (int ni = 0; ni < 4; ++ni) {
                const int edge = ni * 16 + r15;
                const int ui = (8192 + edge * 128 + ks * 32 + khi * 8) ^ ((edge & 7) << 3);
                b[ni] = *(const bf16x8*)(sE + ui);
            }
#pragma unroll
            for (int ni = 0; ni < 4; ++ni) {
                a3[0][ni] = __builtin_amdgcn_mfma_f32_16x16x32_bf16(a0, b[ni], a3[0][ni], 0, 0, 0);
                a3[1][ni] = __builtin_amdgcn_mfma_f32_16x16x32_bf16(a1, b[ni], a3[1][ni], 0, 0, 0);
            }
        }
        const float4 bb0 = *(const float4*)&nb3[fb + rhi];
        const float4 bb1 = *(const float4*)&nb3[fb + 16 + rhi];
#pragma unroll
        for (int mi = 0; mi < 2; ++mi) {
            const float4 bb = mi ? bb1 : bb0;
#pragma unroll
            for (int ni = 0; ni < 4; ++ni) {
                const int n = n0 + ni * 16 + r15;
                if (n < N_NODES) {
                    const size_t o = (size_t)n * 128 + fb + mi * 16 + rhi;
                    const float4 hv = *(const float4*)&h[o];
                    float4 ov;
                    ov.x = hv.x + a3[mi][ni][0] + bb.x;
                    ov.y = hv.y + a3[mi][ni][1] + bb.y;
                    ov.z = hv.z + a3[mi][ni][2] + bb.z;
                    ov.w = hv.w + a3[mi][ni][3] + bb.w;
                    *(float4*)&hout[o] = ov;
                }
            }
        }
    }
}

extern "C" void kernel_launch(void* const* d_in, const int* in_sizes, int n_in,
                              void* d_out, int out_size, void* d_ws, size_t ws_size,
                              hipStream_t stream) {
    const float* x   = (const float*)d_in[0];
    const float* h   = (const float*)d_in[1];
    const int*   ei  = (const int*)d_in[2];
    const float* ew1 = (const float*)d_in[3];
    const float* eb1 = (const float*)d_in[4];
    const float* ew2 = (const float*)d_in[5];
    const float* eb2 = (const float*)d_in[6];
    const float* ew3 = (const float*)d_in[7];
    const float* eb3 = (const float*)d_in[8];
    const float* cw1 = (const float*)d_in[9];
    const float* cb1 = (const float*)d_in[10];
    const float* cw2 = (const float*)d_in[11];
    const float* cb2 = (const float*)d_in[12];
    const float* nw1 = (const float*)d_in[13];
    const float* nb1 = (const float*)d_in[14];
    const float* nw2 = (const float*)d_in[15];
    const float* nb2 = (const float*)d_in[16];
    const float* nw3 = (const float*)d_in[17];
    const float* nb3 = (const float*)d_in[18];

    float* out  = (float*)d_out;
    float* xout = out;                       // [50000,3]
    float* hout = out + (size_t)N_NODES * 3; // [50000,128]
    ushort_t* wsu = (ushort_t*)d_ws;

    ushort_t* maggr = wsu + U_MAGGR;
    const ushort_t* hb  = wsu + U_HB;
    const ushort_t* wab = wsu + U_W1B;       // Wab 256x128
    const ushort_t* w2b = wsu + U_W2B;
    const ushort_t* w3b = wsu + U_W3B;
    const ushort_t* c1b = wsu + U_C1B;
    const ushort_t* n1b = wsu + U_N1B;
    const ushort_t* n2b = wsu + U_N2B;
    const ushort_t* n3b = wsu + U_N3B;
    const float* w1d2 = (const float*)(wsu + U_W1D2);
    ushort_t* wcb = wsu + U_WC;
    float* bcv = (float*)(wsu + U_BC);
    int2* sd = (int2*)(wsu + U_SD);
    unsigned int* cnt = (unsigned int*)(wsu + U_CNT);
    unsigned int* ptr = (unsigned int*)(wsu + U_PTR);
    unsigned int* rank = (unsigned int*)(wsu + U_RANK);

    // AB table (bf16 [N][256] = 25.6 MB) stashed in the hout region of d_out;
    // node_kernel fully overwrites hout afterwards.
    ushort_t* abp = (ushort_t*)hout;

    hipMemsetAsync(cnt, 0, 50048 * sizeof(unsigned int), stream);

    const long prep_total = 800000L + 800000L + 32768 + 3 * 16384 + 32768 + 2 * 16384 + 128 + 37500 + N_EDGES;
    const int prep_blocks = (int)((prep_total + 255) / 256);
    prep_kernel<<<prep_blocks, 256, 0, stream>>>(x, h, ew1, ew2, ew3, cw1, nw1, nw2, nw3,
                                                 ei, wsu, xout);

    const int nAB = (N_NODES + 63) / 64;     // 782; +1 = Wc block, +2 = scan block
    ab_kernel<<<nAB + 2, 256, 0, stream>>>(hb, wab, eb1, abp,
                                           c1b, ew3, eb3, cb1, wcb, bcv,
                                           cnt, ptr, nAB);

    scatter_kernel<<<(N_EDGES + 255) / 256, 256, 0, stream>>>(ei, ptr, rank, sd);

    edge_kernel<<<N_EDGES / EDG, 512, 0, stream>>>(x, abp, sd,
                                                   w1d2, w2b, eb2, w3b, eb3,
                                                   wcb, bcv, cw2, cb2,
                                                   xout, maggr);

    node_kernel<<<(N_NODES + 63) / 64, 256, 0, stream>>>(h, hb, maggr,
                                                         n1b, nb1, n2b, nb2, n3b, nb3,
                                                         hout);
}